// Round 15
// baseline (1506.793 us; speedup 1.0000x reference)
//
#include <hip/hip_runtime.h>
#include <hip/hip_bf16.h>

#define B_ 32
#define T_ 512
#define L_ 128
#define INC_ 512
#define D_ 512
#define H_ 8
#define HD_ 64
#define NL_ 6
#define DFF_ 1024
#define V_ 8000
#define LDSK 40  // gemm LDS row stride (bf16)
#define AST 72   // attn LDS row stride (bf16)

typedef __bf16 bfr;
typedef __attribute__((ext_vector_type(8))) __bf16 bf16x8;
typedef __attribute__((ext_vector_type(4))) __bf16 bf16x4;
typedef __attribute__((ext_vector_type(4))) float f32x4;

// ---- batched f32 -> bf16 convert (weights) ----
struct ConvDesc { const float* src; bfr* dst; int n; int blk0; };
struct ConvTable { ConvDesc e[12]; int ne; };

__global__ void conv_many_kernel(ConvTable tab)
{
    int b = blockIdx.x;
    for (int i = 0; i < tab.ne; ++i) {
        const ConvDesc d = tab.e[i];
        int nb = (d.n + 255) >> 8;
        if (b >= d.blk0 && b < d.blk0 + nb) {
            int g = (b - d.blk0) * 256 + threadIdx.x;
            if (g < d.n) d.dst[g] = (bfr)d.src[g];
            return;
        }
    }
}

// bijective XCD-chunk remap (m204) + GROUP_M tile raster -> (pm, pn)
__device__ __forceinline__ void tile_map(int bid, int nbm, int nbn, int& pm, int& pn)
{
    int nwg = nbm * nbn;
    int q = nwg >> 3, r = nwg & 7;
    int xcd = bid & 7, idx = bid >> 3;
    int wgid = (xcd < r ? xcd * (q + 1) : r * (q + 1) + (xcd - r) * q) + idx;
    const int GROUP = 8;
    int per_group = GROUP * nbn;
    int gid = wgid / per_group;
    int first = gid * GROUP;
    int gsz = min(nbm - first, GROUP);
    int rem = wgid - gid * per_group;
    pm = first + rem % gsz;
    pn = rem / gsz;
}

// ---- GEMM, A = f32 (converted in-kernel), W bf16. Prologue only. OUT: 0=f32, 1=bf16 ----
template <int OUT>
__global__ __launch_bounds__(256) void gemm_split(
    const float* __restrict__ A, const bfr* __restrict__ Whi,
    const float* __restrict__ bias, float* __restrict__ Cf, bfr* __restrict__ Cb,
    int M, int N, int K)
{
    __shared__ bfr Ah_s[128 * LDSK];
    __shared__ bfr Wh_s[64 * LDSK];
    const int t = threadIdx.x;
    const int bm = blockIdx.y * 128, bn = blockIdx.x * 64;
    const int w = t >> 6, lane = t & 63;
    const int wm = w >> 1, wn = w & 1;
    const int fr = lane & 15, kq = lane >> 4;
    const int ar = t >> 1, ah = (t & 1) * 16;
    const int wr = t >> 2, wk = (t & 3) * 8;

    f32x4 acc[4][2] = {};

    for (int k0 = 0; k0 < K; k0 += 32) {
        {
            const float* ap = A + (size_t)(bm + ar) * K + (k0 + ah);
            float4 v0 = ((const float4*)ap)[0];
            float4 v1 = ((const float4*)ap)[1];
            float4 v2 = ((const float4*)ap)[2];
            float4 v3 = ((const float4*)ap)[3];
            float xs[16] = {v0.x, v0.y, v0.z, v0.w, v1.x, v1.y, v1.z, v1.w,
                            v2.x, v2.y, v2.z, v2.w, v3.x, v3.y, v3.z, v3.w};
            bf16x8 h0, h1;
#pragma unroll
            for (int i = 0; i < 8; ++i) h0[i] = (bfr)xs[i];
#pragma unroll
            for (int i = 0; i < 8; ++i) h1[i] = (bfr)xs[8 + i];
            *(bf16x8*)(Ah_s + ar * LDSK + ah) = h0;
            *(bf16x8*)(Ah_s + ar * LDSK + ah + 8) = h1;
        }
        *(bf16x8*)(Wh_s + wr * LDSK + wk) = *(const bf16x8*)(Whi + (size_t)(bn + wr) * K + (k0 + wk));
        __syncthreads();
        bf16x8 Afh[4], Wfh[2];
#pragma unroll
        for (int i = 0; i < 4; ++i)
            Afh[i] = *(const bf16x8*)(Ah_s + (wm * 64 + i * 16 + fr) * LDSK + kq * 8);
#pragma unroll
        for (int j = 0; j < 2; ++j)
            Wfh[j] = *(const bf16x8*)(Wh_s + (wn * 32 + j * 16 + fr) * LDSK + kq * 8);
#pragma unroll
        for (int i = 0; i < 4; ++i)
#pragma unroll
            for (int j = 0; j < 2; ++j)
                acc[i][j] = __builtin_amdgcn_mfma_f32_16x16x32_bf16(Afh[i], Wfh[j], acc[i][j], 0, 0, 0);
        __syncthreads();
    }
#pragma unroll
    for (int i = 0; i < 4; ++i) {
        int row0 = bm + wm * 64 + i * 16 + (lane >> 4) * 4;
#pragma unroll
        for (int j = 0; j < 2; ++j) {
            int col = bn + wn * 32 + j * 16 + fr;
            float bj = bias[col];
#pragma unroll
            for (int r = 0; r < 4; ++r) {
                float v = acc[i][j][r] + bj;
                if (OUT == 0) Cf[(size_t)(row0 + r) * N + col] = v;
                else Cb[(size_t)(row0 + r) * N + col] = (bfr)v;
            }
        }
    }
}

// ---- GEMM, A bf16, W bf16 (1-term). BM in {64,128}; 1D grid + swizzle ----
// OUT: 0=f32, 1=bf16
template <int ACT, int OUT, int BM>
__global__ __launch_bounds__(256, 2) void gemm_ps(
    const bfr* __restrict__ Ahi,
    const bfr* __restrict__ Whi,
    const float* __restrict__ bias, float* __restrict__ Cf,
    bfr* __restrict__ Chi, int M, int N, int K)
{
    constexpr int MF = BM / 32;
    __shared__ bfr Ah_s[BM * LDSK];
    __shared__ bfr Wh_s[64 * LDSK];
    const int t = threadIdx.x;
    int pm, pn;
    tile_map(blockIdx.x, M / BM, N / 64, pm, pn);
    const int bm = pm * BM, bn = pn * 64;
    const int w = t >> 6, lane = t & 63;
    const int wm = w >> 1, wn = w & 1;
    const int fr = lane & 15, kq = lane >> 4;
    const int wr = t >> 2, wk = (t & 3) * 8;

    f32x4 acc[MF][2] = {};

    for (int k0 = 0; k0 < K; k0 += 32) {
        if constexpr (BM == 128) {
            const int ar = t >> 1, ah = (t & 1) * 16;
            const bfr* ap = Ahi + (size_t)(bm + ar) * K + (k0 + ah);
            *(bf16x8*)(Ah_s + ar * LDSK + ah) = *(const bf16x8*)ap;
            *(bf16x8*)(Ah_s + ar * LDSK + ah + 8) = *(const bf16x8*)(ap + 8);
        } else {
            const int ar = t >> 2, ah = (t & 3) * 8;
            *(bf16x8*)(Ah_s + ar * LDSK + ah) = *(const bf16x8*)(Ahi + (size_t)(bm + ar) * K + (k0 + ah));
        }
        *(bf16x8*)(Wh_s + wr * LDSK + wk) = *(const bf16x8*)(Whi + (size_t)(bn + wr) * K + (k0 + wk));
        __syncthreads();
        bf16x8 Afh[MF], Wfh[2];
#pragma unroll
        for (int i = 0; i < MF; ++i)
            Afh[i] = *(const bf16x8*)(Ah_s + (wm * (BM / 2) + i * 16 + fr) * LDSK + kq * 8);
#pragma unroll
        for (int j = 0; j < 2; ++j)
            Wfh[j] = *(const bf16x8*)(Wh_s + (wn * 32 + j * 16 + fr) * LDSK + kq * 8);
#pragma unroll
        for (int i = 0; i < MF; ++i)
#pragma unroll
            for (int j = 0; j < 2; ++j)
                acc[i][j] = __builtin_amdgcn_mfma_f32_16x16x32_bf16(Afh[i], Wfh[j], acc[i][j], 0, 0, 0);
        __syncthreads();
    }
#pragma unroll
    for (int i = 0; i < MF; ++i) {
        int row0 = bm + wm * (BM / 2) + i * 16 + (lane >> 4) * 4;
#pragma unroll
        for (int j = 0; j < 2; ++j) {
            int col = bn + wn * 32 + j * 16 + fr;
            float bj = bias[col];
#pragma unroll
            for (int r = 0; r < 4; ++r) {
                float v = acc[i][j][r] + bj;
                if (ACT == 1) v = 0.5f * v * (1.0f + erff(v * 0.70710678118654752f));
                size_t idx = (size_t)(row0 + r) * N + col;
                if (OUT == 0) Cf[idx] = v;
                else Chi[idx] = (bfr)v;
            }
        }
    }
}

// ---- fused GEMM (N=512) + bias + residual + LayerNorm ----
// Block: 32 rows x full 512 cols; 4 waves = 2 row-stripes x 2 col-halves.
// resid (f32) updated in place; bf16 image written to thi.
__global__ __launch_bounds__(256, 2) void gemm_ln(
    const bfr* __restrict__ Ahi, const bfr* __restrict__ Whi,
    const float* __restrict__ bias,
    float* __restrict__ resid, const float* __restrict__ g, const float* __restrict__ bb,
    bfr* __restrict__ thi, int K)
{
    __shared__ bfr A_s[32 * LDSK];
    __shared__ bfr W_s[512 * LDSK];
    __shared__ float redS[32][2];
    __shared__ float redQ[32][2];
    const int t = threadIdx.x;
    const int w = t >> 6, lane = t & 63;
    const int s = w >> 1, c = w & 1;          // row-stripe, col-half
    const int fr = lane & 15, kq = lane >> 4;
    const int bm = blockIdx.x * 32;

    f32x4 acc[16] = {};

    for (int k0 = 0; k0 < K; k0 += 32) {
        {   // A: 32 rows x 32 k; 4 bf16 per thread
            const int ar = t >> 3, ah = (t & 7) * 4;
            *(bf16x4*)(A_s + ar * LDSK + ah) = *(const bf16x4*)(Ahi + (size_t)(bm + ar) * K + (k0 + ah));
        }
        {   // W: 512 rows x 32 k; 2 rows per thread
            const int wr = t * 2;
            const bfr* wp = Whi + (size_t)wr * K + k0;
#pragma unroll
            for (int q = 0; q < 4; ++q)
                *(bf16x8*)(W_s + wr * LDSK + q * 8) = *(const bf16x8*)(wp + q * 8);
            wp += K;
#pragma unroll
            for (int q = 0; q < 4; ++q)
                *(bf16x8*)(W_s + (wr + 1) * LDSK + q * 8) = *(const bf16x8*)(wp + q * 8);
        }
        __syncthreads();
        bf16x8 Af = *(const bf16x8*)(A_s + (s * 16 + fr) * LDSK + kq * 8);
#pragma unroll
        for (int j = 0; j < 16; ++j) {
            bf16x8 Wf = *(const bf16x8*)(W_s + (c * 256 + j * 16 + fr) * LDSK + kq * 8);
            acc[j] = __builtin_amdgcn_mfma_f32_16x16x32_bf16(Af, Wf, acc[j], 0, 0, 0);
        }
        __syncthreads();
    }

    // epilogue: x = acc + bias + resid; row stats; LN
    float sum[4] = {}, sq[4] = {};
#pragma unroll
    for (int j = 0; j < 16; ++j) {
        int col = c * 256 + j * 16 + fr;
        float bj = bias[col];
#pragma unroll
        for (int r = 0; r < 4; ++r) {
            int row = bm + s * 16 + kq * 4 + r;
            float x = acc[j][r] + bj + resid[(size_t)row * D_ + col];
            acc[j][r] = x;
            sum[r] += x;
            sq[r] += x * x;
        }
    }
#pragma unroll
    for (int off = 1; off < 16; off <<= 1) {
#pragma unroll
        for (int r = 0; r < 4; ++r) {
            sum[r] += __shfl_xor(sum[r], off);
            sq[r] += __shfl_xor(sq[r], off);
        }
    }
    if (fr == 0) {
#pragma unroll
        for (int r = 0; r < 4; ++r) {
            redS[s * 16 + kq * 4 + r][c] = sum[r];
            redQ[s * 16 + kq * 4 + r][c] = sq[r];
        }
    }
    __syncthreads();
#pragma unroll
    for (int r = 0; r < 4; ++r) {
        int ri = s * 16 + kq * 4 + r;
        float S = redS[ri][0] + redS[ri][1];
        float Q = redQ[ri][0] + redQ[ri][1];
        float mean = S * (1.0f / D_);
        float var = Q * (1.0f / D_) - mean * mean;
        float inv = 1.0f / sqrtf(var + 1e-5f);
        int row = bm + ri;
#pragma unroll
        for (int j = 0; j < 16; ++j) {
            int col = c * 256 + j * 16 + fr;
            float y = (acc[j][r] - mean) * inv * g[col] + bb[col];
            resid[(size_t)row * D_ + col] = y;
            thi[(size_t)row * D_ + col] = (bfr)y;
        }
    }
}

// ---- fused flash attention, bf16 inputs; RoPE folded in when CAUSAL ----
template <int TK, int CAUSAL>
__global__ __launch_bounds__(256) void attn_kernel(
    const bfr* __restrict__ Qg, int qstr,
    const bfr* __restrict__ Kg, const bfr* __restrict__ Vg, int kvstr,
    const int* __restrict__ pad,
    const float* __restrict__ cosT, const float* __restrict__ sinT,
    bfr* __restrict__ Ohi)
{
    __shared__ bfr Qs[64 * AST];
    __shared__ bfr Ks[64 * AST];
    __shared__ bfr VTs[64 * AST];
    __shared__ bfr Ps[64 * AST];
    const int bidx = blockIdx.x;
    const int qt = bidx & 1, bh = bidx >> 1;
    const int h = bh & 7, b = bh >> 3;
    const int t = threadIdx.x;
    const int w = t >> 6, lane = t & 63;
    const int l4 = lane & 15, hi4 = lane >> 4;
    const int q0 = qt * 64;
    const int srow = t >> 2, ht = t & 3;

    if (CAUSAL) {
        int qrow = q0 + srow;
        const bfr* qp = Qg + (size_t)(b * L_ + qrow) * qstr + h * HD_ + ht * 8;
        bf16x8 a = *(const bf16x8*)qp;
        bf16x8 bb = *(const bf16x8*)(qp + 32);
        bf16x8 o1, o2;
#pragma unroll
        for (int j = 0; j < 8; ++j) {
            float c = cosT[qrow * 32 + ht * 8 + j], s = sinT[qrow * 32 + ht * 8 + j];
            float x1 = (float)a[j], x2 = (float)bb[j];
            o1[j] = (bfr)(x1 * c - x2 * s);
            o2[j] = (bfr)(x2 * c + x1 * s);
        }
        *(bf16x8*)(Qs + srow * AST + ht * 8) = o1;
        *(bf16x8*)(Qs + srow * AST + ht * 8 + 32) = o2;
    } else {
        const bfr* qp = Qg + (size_t)(b * L_ + q0 + srow) * qstr + h * HD_ + ht * 16;
        *(bf16x8*)(Qs + srow * AST + ht * 16) = *(const bf16x8*)qp;
        *(bf16x8*)(Qs + srow * AST + ht * 16 + 8) = *(const bf16x8*)(qp + 8);
    }

    f32x4 o_acc[4] = {};
    float m_run[4], l_run[4];
#pragma unroll
    for (int r = 0; r < 4; ++r) { m_run[r] = -1e30f; l_run[r] = 0.f; }

    const int NT = CAUSAL ? (qt + 1) : (TK / 64);
    for (int kt = 0; kt < NT; ++kt) {
        __syncthreads();
        if (CAUSAL) {
            int krow = kt * 64 + srow;
            const bfr* kp = Kg + (size_t)(b * TK + krow) * kvstr + h * HD_ + ht * 8;
            bf16x8 a = *(const bf16x8*)kp;
            bf16x8 bb = *(const bf16x8*)(kp + 32);
            bf16x8 o1, o2;
#pragma unroll
            for (int j = 0; j < 8; ++j) {
                float c = cosT[krow * 32 + ht * 8 + j], s = sinT[krow * 32 + ht * 8 + j];
                float x1 = (float)a[j], x2 = (float)bb[j];
                o1[j] = (bfr)(x1 * c - x2 * s);
                o2[j] = (bfr)(x2 * c + x1 * s);
            }
            *(bf16x8*)(Ks + srow * AST + ht * 8) = o1;
            *(bf16x8*)(Ks + srow * AST + ht * 8 + 32) = o2;
        } else {
            const bfr* kp = Kg + (size_t)(b * TK + kt * 64 + srow) * kvstr + h * HD_ + ht * 16;
            *(bf16x8*)(Ks + srow * AST + ht * 16) = *(const bf16x8*)kp;
            *(bf16x8*)(Ks + srow * AST + ht * 16 + 8) = *(const bf16x8*)(kp + 8);
        }
        {
            const bfr* vp = Vg + (size_t)(b * TK + kt * 64 + srow) * kvstr + h * HD_ + ht * 16;
            bf16x8 v0 = *(const bf16x8*)vp;
            bf16x8 v1 = *(const bf16x8*)(vp + 8);
#pragma unroll
            for (int i = 0; i < 8; ++i) VTs[(ht * 16 + i) * AST + srow] = v0[i];
#pragma unroll
            for (int i = 0; i < 8; ++i) VTs[(ht * 16 + 8 + i) * AST + srow] = v1[i];
        }
        __syncthreads();

        f32x4 s[4] = {};
#pragma unroll
        for (int kk = 0; kk < 64; kk += 32) {
            bf16x8 a = *(const bf16x8*)(Qs + (w * 16 + l4) * AST + kk + hi4 * 8);
#pragma unroll
            for (int n = 0; n < 4; ++n) {
                bf16x8 bb = *(const bf16x8*)(Ks + (n * 16 + l4) * AST + kk + hi4 * 8);
                s[n] = __builtin_amdgcn_mfma_f32_16x16x32_bf16(a, bb, s[n], 0, 0, 0);
            }
        }
        float madd[4];
        if (!CAUSAL) {
#pragma unroll
            for (int n = 0; n < 4; ++n)
                madd[n] = pad[b * TK + kt * 64 + n * 16 + l4] ? -1e30f : 0.f;
        }
#pragma unroll
        for (int r = 0; r < 4; ++r) {
            int qrow = q0 + w * 16 + hi4 * 4 + r;
            float sv[4];
#pragma unroll
            for (int n = 0; n < 4; ++n) {
                float x = s[n][r] * 0.125f;
                if (CAUSAL) {
                    int col = kt * 64 + n * 16 + l4;
                    if (col > qrow) x = -1e30f;
                } else x += madd[n];
                sv[n] = x;
            }
            float mx = fmaxf(fmaxf(sv[0], sv[1]), fmaxf(sv[2], sv[3]));
#pragma unroll
            for (int off = 1; off < 16; off <<= 1) mx = fmaxf(mx, __shfl_xor(mx, off));
            float mnew = fmaxf(m_run[r], mx);
            float alpha = expf(m_run[r] - mnew);
            float pv[4], psum = 0.f;
#pragma unroll
            for (int n = 0; n < 4; ++n) { pv[n] = expf(sv[n] - mnew); psum += pv[n]; }
#pragma unroll
            for (int off = 1; off < 16; off <<= 1) psum += __shfl_xor(psum, off);
            l_run[r] = l_run[r] * alpha + psum;
            m_run[r] = mnew;
#pragma unroll
            for (int n = 0; n < 4; ++n) o_acc[n][r] *= alpha;
#pragma unroll
            for (int n = 0; n < 4; ++n)
                Ps[(w * 16 + hi4 * 4 + r) * AST + n * 16 + l4] = (bfr)pv[n];
        }
#pragma unroll
        for (int kk = 0; kk < 64; kk += 32) {
            bf16x8 pa = *(const bf16x8*)(Ps + (w * 16 + l4) * AST + kk + hi4 * 8);
#pragma unroll
            for (int n = 0; n < 4; ++n) {
                bf16x8 vb = *(const bf16x8*)(VTs + (n * 16 + l4) * AST + kk + hi4 * 8);
                o_acc[n] = __builtin_amdgcn_mfma_f32_16x16x32_bf16(pa, vb, o_acc[n], 0, 0, 0);
            }
        }
    }
#pragma unroll
    for (int r = 0; r < 4; ++r) {
        float inv = 1.0f / l_run[r];
        int qrow = q0 + w * 16 + hi4 * 4 + r;
#pragma unroll
        for (int n = 0; n < 4; ++n)
            Ohi[(size_t)(b * L_ + qrow) * D_ + h * HD_ + n * 16 + l4] = (bfr)(o_acc[n][r] * inv);
    }
}

__global__ void rope_tables_kernel(float* __restrict__ cosT, float* __restrict__ sinT)
{
    int gid = blockIdx.x * blockDim.x + threadIdx.x;
    if (gid >= L_ * 32) return;
    int l = gid >> 5, i = gid & 31;
    float inv = powf(10000.0f, -(float)(2 * i) / (float)HD_);
    float ang = (float)l * inv;
    cosT[gid] = cosf(ang);
    sinT[gid] = sinf(ang);
}

__global__ void embed_kernel(const int* __restrict__ targets, const float* __restrict__ emb,
                             float* __restrict__ tgt, bfr* __restrict__ thi)
{
    int gid = blockIdx.x * blockDim.x + threadIdx.x;
    if (gid >= B_ * L_ * D_) return;
    int d = gid & (D_ - 1);
    int r = gid >> 9;
    int tok = targets[r];
    float x = emb[(size_t)tok * D_ + d] * 22.62741699796952f;
    tgt[gid] = x;
    thi[gid] = (bfr)x;
}

__global__ void pad_kernel(const float* __restrict__ mem, int* __restrict__ pad)
{
    int gid = blockIdx.x * blockDim.x + threadIdx.x;
    if (gid >= B_ * T_) return;
    const float* p = mem + (size_t)gid * D_;
    float s = 0.f;
    for (int d = 0; d < D_; ++d) s += fabsf(p[d]);
    pad[gid] = (s == 0.0f) ? 1 : 0;
}

__global__ void copyf_kernel(const float* __restrict__ in, float* __restrict__ out, int n)
{
    int gid = blockIdx.x * blockDim.x + threadIdx.x;
    if (gid < n) out[gid] = in[gid];
}

__global__ void fillf_kernel(float* p, float v, size_t n)
{
    size_t gid = (size_t)blockIdx.x * 256 + threadIdx.x;
    if (gid < n) p[gid] = v;
}

extern "C" void kernel_launch(void* const* d_in, const int* in_sizes, int n_in,
                              void* d_out, int out_size, void* d_ws, size_t ws_size,
                              hipStream_t stream)
{
    const float* enc    = (const float*)d_in[0];
    const int*   tg     = (const int*)d_in[1];
    const float* emb    = (const float*)d_in[2];
    const float* inp_w  = (const float*)d_in[3];
    const float* inp_b  = (const float*)d_in[4];
    const float* out_w  = (const float*)d_in[5];
    const float* out_b  = (const float*)d_in[6];
    const float* qw     = (const float*)d_in[7];
    const float* qb     = (const float*)d_in[8];
    const float* kw     = (const float*)d_in[9];
    const float* kb     = (const float*)d_in[10];
    const float* vw     = (const float*)d_in[11];
    const float* vb     = (const float*)d_in[12];
    const float* ow     = (const float*)d_in[13];
    const float* ob     = (const float*)d_in[14];
    const float* mha_w  = (const float*)d_in[15];
    const float* mha_b  = (const float*)d_in[16];
    const float* mha_ow = (const float*)d_in[17];
    const float* mha_ob = (const float*)d_in[18];
    const float* w1     = (const float*)d_in[19];
    const float* b1     = (const float*)d_in[20];
    const float* w2     = (const float*)d_in[21];
    const float* b2     = (const float*)d_in[22];
    const float* ln1g   = (const float*)d_in[23];
    const float* ln1b   = (const float*)d_in[24];
    const float* ln2g   = (const float*)d_in[25];
    const float* ln2b   = (const float*)d_in[26];
    const float* ln3g   = (const float*)d_in[27];
    const float* ln3b   = (const float*)d_in[28];

    const int BL = B_ * L_;        // 4096
    const int BT = B_ * T_;        // 16384
    const size_t N_LOGITS = (size_t)BL * V_;
    const int D2 = D_ * D_;        // 262144

    const size_t WS_NEEDED =
        (size_t)BT * 1024 * sizeof(bfr)
        + (size_t)BL * D_ * sizeof(float)
        + (size_t)BL * D_ * sizeof(bfr)
        + (size_t)2 * L_ * 32 * sizeof(float) + (size_t)BT * sizeof(int)
        + (size_t)V_ * D_ * sizeof(bfr);
    if (ws_size < WS_NEEDED) {
        fillf_kernel<<<((size_t)out_size + 255) / 256, 256, 0, stream>>>((float*)d_out, 0.f, (size_t)out_size);
        return;
    }
    bfr*   f_KVb = (bfr*)d_ws;                          // [BT,1024]: K2 | V2
    float* f_tgt = (float*)(f_KVb + (size_t)BT * 1024);
    bfr*   tgt_hi = (bfr*)(f_tgt + (size_t)BL * D_);
    float* f_cos = (float*)(tgt_hi + (size_t)BL * D_);
    float* f_sin = f_cos + (size_t)L_ * 32;
    int*   f_pad = (int*)(f_sin + (size_t)L_ * 32);
    bfr*   ow_hi = (bfr*)(f_pad + BT);

    bfr* wp = (bfr*)d_out;
    bfr* qkvw_hi = wp;  wp += 3 * D2;
    bfr* inp_hi  = wp;  wp += D2;
    bfr* mha_hi  = wp;  wp += 3 * D2;
    bfr* o_hi    = wp;  wp += D2;
    bfr* mo_hi   = wp;  wp += D2;
    bfr* w1_hi   = wp;  wp += DFF_ * D_;
    bfr* w2_hi   = wp;  wp += D_ * DFF_;
    float* f_qkvb = (float*)wp;                 // [1536]
    float* lr    = f_qkvb + 3 * D_;
    bfr*   qkv   = (bfr*)lr;                             // [BL,1536]
    bfr*   qcr   = qkv + (size_t)BL * 3 * D_;            // [BL,512]
    bfr*   t1_hi = qcr + (size_t)BL * D_;                // [BL,512]
    bfr*   ffh_hi = t1_hi + (size_t)BL * D_;             // [BL,1024]
    float* f_mem = lr;  // prologue-only alias (BT*D f32 = 33.5MB <= layer region 25.2MB? no:)
    // layer region = qkv..ffh_hi = BL*(1536+512+512+1024)*2B = 29.4MB < BT*D*4 = 33.5MB
    // -> give f_mem its own tail region instead:
    float* f_mem2 = (float*)(ffh_hi + (size_t)BL * DFF_);

    // single batched weight convert (bf16)
    {
        ConvTable tab{};
        int blk = 0, ne = 0;
        auto add = [&](const float* s, bfr* d, int n) {
            tab.e[ne] = {s, d, n, blk};
            blk += (n + 255) >> 8;
            ++ne;
        };
        add(qw, qkvw_hi, D2);
        add(kw, qkvw_hi + D2, D2);
        add(vw, qkvw_hi + 2 * D2, D2);
        add(inp_w, inp_hi, D2);
        add(mha_w, mha_hi, 3 * D2);
        add(ow, o_hi, D2);
        add(mha_ow, mo_hi, D2);
        add(w1, w1_hi, DFF_ * D_);
        add(w2, w2_hi, D_ * DFF_);
        add(out_w, ow_hi, V_ * D_);
        tab.ne = ne;
        conv_many_kernel<<<blk, 256, 0, stream>>>(tab);
    }
    copyf_kernel<<<2, 256, 0, stream>>>(qb, f_qkvb, D_);
    copyf_kernel<<<2, 256, 0, stream>>>(kb, f_qkvb + D_, D_);
    copyf_kernel<<<2, 256, 0, stream>>>(vb, f_qkvb + 2 * D_, D_);

    rope_tables_kernel<<<(L_ * 32 + 255) / 256, 256, 0, stream>>>(f_cos, f_sin);
    embed_kernel<<<(BL * D_ + 255) / 256, 256, 0, stream>>>(tg, emb, f_tgt, tgt_hi);

    // prologue: memory f32, pad mask, fused K2|V2 (bf16, N=1024)
    gemm_split<0><<<dim3(D_ / 64, BT / 128), 256, 0, stream>>>(enc, inp_hi, inp_b, f_mem2, nullptr, BT, D_, INC_);
    pad_kernel<<<(BT + 255) / 256, 256, 0, stream>>>(f_mem2, f_pad);
    gemm_split<1><<<dim3(1024 / 64, BT / 128), 256, 0, stream>>>(f_mem2, mha_hi + (size_t)D2, mha_b + D_, nullptr, f_KVb, BT, 1024, D_);

    for (int layer = 0; layer < NL_; ++layer) {
        // self attention
        gemm_ps<0, 1, 64><<<(BL / 64) * (3 * D_ / 64), 256, 0, stream>>>(tgt_hi, qkvw_hi, f_qkvb, nullptr, qkv, BL, 3 * D_, D_);
        attn_kernel<L_, 1><<<B_ * H_ * 2, 256, 0, stream>>>(qkv, 3 * D_, qkv + D_, qkv + 2 * D_, 3 * D_, nullptr, f_cos, f_sin, t1_hi);
        gemm_ln<<<BL / 32, 256, 0, stream>>>(t1_hi, o_hi, ob, f_tgt, ln1g, ln1b, tgt_hi, D_);
        // cross attention
        gemm_ps<0, 1, 64><<<(BL / 64) * (D_ / 64), 256, 0, stream>>>(tgt_hi, mha_hi, mha_b, nullptr, qcr, BL, D_, D_);
        attn_kernel<T_, 0><<<B_ * H_ * 2, 256, 0, stream>>>(qcr, D_, f_KVb, f_KVb + D_, 1024, f_pad, nullptr, nullptr, t1_hi);
        gemm_ln<<<BL / 32, 256, 0, stream>>>(t1_hi, mo_hi, mha_ob, f_tgt, ln2g, ln2b, tgt_hi, D_);
        // FFN
        gemm_ps<1, 1, 64><<<(BL / 64) * (DFF_ / 64), 256, 0, stream>>>(tgt_hi, w1_hi, b1, nullptr, ffh_hi, BL, DFF_, D_);
        gemm_ln<<<BL / 32, 256, 0, stream>>>(ffh_hi, w2_hi, b2, f_tgt, ln3g, ln3b, tgt_hi, DFF_);
    }

    // all d_out scratch dead; outputs f32
    float* o_logits = (float*)d_out;
    float* o_tgt = o_logits + N_LOGITS;
    gemm_ps<0, 0, 128><<<(BL / 128) * (V_ / 64), 256, 0, stream>>>(tgt_hi, ow_hi, out_b, o_logits, nullptr, BL, V_, D_);
    copyf_kernel<<<(BL * D_ + 255) / 256, 256, 0, stream>>>(f_tgt, o_tgt, BL * D_);
}

// Round 16
// 1095.125 us; speedup vs baseline: 1.3759x; 1.3759x over previous
//
#include <hip/hip_runtime.h>
#include <hip/hip_bf16.h>

#define B_ 32
#define T_ 512
#define L_ 128
#define INC_ 512
#define D_ 512
#define H_ 8
#define HD_ 64
#define NL_ 6
#define DFF_ 1024
#define V_ 8000
#define LDSK 40  // gemm LDS row stride (bf16)
#define AST 72   // attn LDS row stride (bf16)

typedef __bf16 bfr;
typedef __attribute__((ext_vector_type(8))) __bf16 bf16x8;
typedef __attribute__((ext_vector_type(4))) __bf16 bf16x4;
typedef __attribute__((ext_vector_type(4))) float f32x4;

// ---- batched f32 -> bf16 convert (weights) ----
struct ConvDesc { const float* src; bfr* dst; int n; int blk0; };
struct ConvTable { ConvDesc e[12]; int ne; };

__global__ void conv_many_kernel(ConvTable tab)
{
    int b = blockIdx.x;
    for (int i = 0; i < tab.ne; ++i) {
        const ConvDesc d = tab.e[i];
        int nb = (d.n + 255) >> 8;
        if (b >= d.blk0 && b < d.blk0 + nb) {
            int g = (b - d.blk0) * 256 + threadIdx.x;
            if (g < d.n) d.dst[g] = (bfr)d.src[g];
            return;
        }
    }
}

__global__ void copy3_kernel(const float* a, const float* b, const float* c, float* dst)
{
    int g = blockIdx.x * 256 + threadIdx.x;
    if (g < D_) dst[g] = a[g];
    else if (g < 2 * D_) dst[g] = b[g - D_];
    else if (g < 3 * D_) dst[g] = c[g - 2 * D_];
}

// bijective XCD-chunk remap (m204) + GROUP_M tile raster -> (pm, pn)
__device__ __forceinline__ void tile_map(int bid, int nbm, int nbn, int& pm, int& pn)
{
    int nwg = nbm * nbn;
    int q = nwg >> 3, r = nwg & 7;
    int xcd = bid & 7, idx = bid >> 3;
    int wgid = (xcd < r ? xcd * (q + 1) : r * (q + 1) + (xcd - r) * q) + idx;
    const int GROUP = 8;
    int per_group = GROUP * nbn;
    int gid = wgid / per_group;
    int first = gid * GROUP;
    int gsz = min(nbm - first, GROUP);
    int rem = wgid - gid * per_group;
    pm = first + rem % gsz;
    pn = rem / gsz;
}

// ---- GEMM, A = f32 (converted in-kernel), W bf16. Prologue only. OUT: 0=f32, 1=bf16 ----
template <int OUT>
__global__ __launch_bounds__(256) void gemm_split(
    const float* __restrict__ A, const bfr* __restrict__ Whi,
    const float* __restrict__ bias, float* __restrict__ Cf, bfr* __restrict__ Cb,
    int M, int N, int K)
{
    __shared__ bfr Ah_s[128 * LDSK];
    __shared__ bfr Wh_s[64 * LDSK];
    const int t = threadIdx.x;
    const int bm = blockIdx.y * 128, bn = blockIdx.x * 64;
    const int w = t >> 6, lane = t & 63;
    const int wm = w >> 1, wn = w & 1;
    const int fr = lane & 15, kq = lane >> 4;
    const int ar = t >> 1, ah = (t & 1) * 16;
    const int wr = t >> 2, wk = (t & 3) * 8;

    f32x4 acc[4][2] = {};

    for (int k0 = 0; k0 < K; k0 += 32) {
        {
            const float* ap = A + (size_t)(bm + ar) * K + (k0 + ah);
            float4 v0 = ((const float4*)ap)[0];
            float4 v1 = ((const float4*)ap)[1];
            float4 v2 = ((const float4*)ap)[2];
            float4 v3 = ((const float4*)ap)[3];
            float xs[16] = {v0.x, v0.y, v0.z, v0.w, v1.x, v1.y, v1.z, v1.w,
                            v2.x, v2.y, v2.z, v2.w, v3.x, v3.y, v3.z, v3.w};
            bf16x8 h0, h1;
#pragma unroll
            for (int i = 0; i < 8; ++i) h0[i] = (bfr)xs[i];
#pragma unroll
            for (int i = 0; i < 8; ++i) h1[i] = (bfr)xs[8 + i];
            *(bf16x8*)(Ah_s + ar * LDSK + ah) = h0;
            *(bf16x8*)(Ah_s + ar * LDSK + ah + 8) = h1;
        }
        *(bf16x8*)(Wh_s + wr * LDSK + wk) = *(const bf16x8*)(Whi + (size_t)(bn + wr) * K + (k0 + wk));
        __syncthreads();
        bf16x8 Afh[4], Wfh[2];
#pragma unroll
        for (int i = 0; i < 4; ++i)
            Afh[i] = *(const bf16x8*)(Ah_s + (wm * 64 + i * 16 + fr) * LDSK + kq * 8);
#pragma unroll
        for (int j = 0; j < 2; ++j)
            Wfh[j] = *(const bf16x8*)(Wh_s + (wn * 32 + j * 16 + fr) * LDSK + kq * 8);
#pragma unroll
        for (int i = 0; i < 4; ++i)
#pragma unroll
            for (int j = 0; j < 2; ++j)
                acc[i][j] = __builtin_amdgcn_mfma_f32_16x16x32_bf16(Afh[i], Wfh[j], acc[i][j], 0, 0, 0);
        __syncthreads();
    }
#pragma unroll
    for (int i = 0; i < 4; ++i) {
        int row0 = bm + wm * 64 + i * 16 + (lane >> 4) * 4;
#pragma unroll
        for (int j = 0; j < 2; ++j) {
            int col = bn + wn * 32 + j * 16 + fr;
            float bj = bias[col];
#pragma unroll
            for (int r = 0; r < 4; ++r) {
                float v = acc[i][j][r] + bj;
                if (OUT == 0) Cf[(size_t)(row0 + r) * N + col] = v;
                else Cb[(size_t)(row0 + r) * N + col] = (bfr)v;
            }
        }
    }
}

// ---- GEMM, A bf16, W bf16 (1-term). BM in {64,128}; 1D grid + swizzle ----
// OUT: 0=f32, 1=bf16
template <int ACT, int OUT, int BM>
__global__ __launch_bounds__(256, 2) void gemm_ps(
    const bfr* __restrict__ Ahi,
    const bfr* __restrict__ Whi,
    const float* __restrict__ bias, float* __restrict__ Cf,
    bfr* __restrict__ Chi, int M, int N, int K)
{
    constexpr int MF = BM / 32;
    __shared__ bfr Ah_s[BM * LDSK];
    __shared__ bfr Wh_s[64 * LDSK];
    const int t = threadIdx.x;
    int pm, pn;
    tile_map(blockIdx.x, M / BM, N / 64, pm, pn);
    const int bm = pm * BM, bn = pn * 64;
    const int w = t >> 6, lane = t & 63;
    const int wm = w >> 1, wn = w & 1;
    const int fr = lane & 15, kq = lane >> 4;
    const int wr = t >> 2, wk = (t & 3) * 8;

    f32x4 acc[MF][2] = {};

    for (int k0 = 0; k0 < K; k0 += 32) {
        if constexpr (BM == 128) {
            const int ar = t >> 1, ah = (t & 1) * 16;
            const bfr* ap = Ahi + (size_t)(bm + ar) * K + (k0 + ah);
            *(bf16x8*)(Ah_s + ar * LDSK + ah) = *(const bf16x8*)ap;
            *(bf16x8*)(Ah_s + ar * LDSK + ah + 8) = *(const bf16x8*)(ap + 8);
        } else {
            const int ar = t >> 2, ah = (t & 3) * 8;
            *(bf16x8*)(Ah_s + ar * LDSK + ah) = *(const bf16x8*)(Ahi + (size_t)(bm + ar) * K + (k0 + ah));
        }
        *(bf16x8*)(Wh_s + wr * LDSK + wk) = *(const bf16x8*)(Whi + (size_t)(bn + wr) * K + (k0 + wk));
        __syncthreads();
        bf16x8 Afh[MF], Wfh[2];
#pragma unroll
        for (int i = 0; i < MF; ++i)
            Afh[i] = *(const bf16x8*)(Ah_s + (wm * (BM / 2) + i * 16 + fr) * LDSK + kq * 8);
#pragma unroll
        for (int j = 0; j < 2; ++j)
            Wfh[j] = *(const bf16x8*)(Wh_s + (wn * 32 + j * 16 + fr) * LDSK + kq * 8);
#pragma unroll
        for (int i = 0; i < MF; ++i)
#pragma unroll
            for (int j = 0; j < 2; ++j)
                acc[i][j] = __builtin_amdgcn_mfma_f32_16x16x32_bf16(Afh[i], Wfh[j], acc[i][j], 0, 0, 0);
        __syncthreads();
    }
#pragma unroll
    for (int i = 0; i < MF; ++i) {
        int row0 = bm + wm * (BM / 2) + i * 16 + (lane >> 4) * 4;
#pragma unroll
        for (int j = 0; j < 2; ++j) {
            int col = bn + wn * 32 + j * 16 + fr;
            float bj = bias[col];
#pragma unroll
            for (int r = 0; r < 4; ++r) {
                float v = acc[i][j][r] + bj;
                if (ACT == 1) v = 0.5f * v * (1.0f + erff(v * 0.70710678118654752f));
                size_t idx = (size_t)(row0 + r) * N + col;
                if (OUT == 0) Cf[idx] = v;
                else Chi[idx] = (bfr)v;
            }
        }
    }
}

// ---- fused flash attention, bf16 inputs; RoPE folded in when CAUSAL ----
template <int TK, int CAUSAL>
__global__ __launch_bounds__(256) void attn_kernel(
    const bfr* __restrict__ Qg, int qstr,
    const bfr* __restrict__ Kg, const bfr* __restrict__ Vg, int kvstr,
    const int* __restrict__ pad,
    const float* __restrict__ cosT, const float* __restrict__ sinT,
    bfr* __restrict__ Ohi)
{
    __shared__ bfr Qs[64 * AST];
    __shared__ bfr Ks[64 * AST];
    __shared__ bfr VTs[64 * AST];
    __shared__ bfr Ps[64 * AST];
    const int bidx = blockIdx.x;
    const int qt = bidx & 1, bh = bidx >> 1;
    const int h = bh & 7, b = bh >> 3;
    const int t = threadIdx.x;
    const int w = t >> 6, lane = t & 63;
    const int l4 = lane & 15, hi4 = lane >> 4;
    const int q0 = qt * 64;
    const int srow = t >> 2, ht = t & 3;

    if (CAUSAL) {
        int qrow = q0 + srow;
        const bfr* qp = Qg + (size_t)(b * L_ + qrow) * qstr + h * HD_ + ht * 8;
        bf16x8 a = *(const bf16x8*)qp;
        bf16x8 bb = *(const bf16x8*)(qp + 32);
        bf16x8 o1, o2;
#pragma unroll
        for (int j = 0; j < 8; ++j) {
            float c = cosT[qrow * 32 + ht * 8 + j], s = sinT[qrow * 32 + ht * 8 + j];
            float x1 = (float)a[j], x2 = (float)bb[j];
            o1[j] = (bfr)(x1 * c - x2 * s);
            o2[j] = (bfr)(x2 * c + x1 * s);
        }
        *(bf16x8*)(Qs + srow * AST + ht * 8) = o1;
        *(bf16x8*)(Qs + srow * AST + ht * 8 + 32) = o2;
    } else {
        const bfr* qp = Qg + (size_t)(b * L_ + q0 + srow) * qstr + h * HD_ + ht * 16;
        *(bf16x8*)(Qs + srow * AST + ht * 16) = *(const bf16x8*)qp;
        *(bf16x8*)(Qs + srow * AST + ht * 16 + 8) = *(const bf16x8*)(qp + 8);
    }

    f32x4 o_acc[4] = {};
    float m_run[4], l_run[4];
#pragma unroll
    for (int r = 0; r < 4; ++r) { m_run[r] = -1e30f; l_run[r] = 0.f; }

    const int NT = CAUSAL ? (qt + 1) : (TK / 64);
    for (int kt = 0; kt < NT; ++kt) {
        __syncthreads();
        if (CAUSAL) {
            int krow = kt * 64 + srow;
            const bfr* kp = Kg + (size_t)(b * TK + krow) * kvstr + h * HD_ + ht * 8;
            bf16x8 a = *(const bf16x8*)kp;
            bf16x8 bb = *(const bf16x8*)(kp + 32);
            bf16x8 o1, o2;
#pragma unroll
            for (int j = 0; j < 8; ++j) {
                float c = cosT[krow * 32 + ht * 8 + j], s = sinT[krow * 32 + ht * 8 + j];
                float x1 = (float)a[j], x2 = (float)bb[j];
                o1[j] = (bfr)(x1 * c - x2 * s);
                o2[j] = (bfr)(x2 * c + x1 * s);
            }
            *(bf16x8*)(Ks + srow * AST + ht * 8) = o1;
            *(bf16x8*)(Ks + srow * AST + ht * 8 + 32) = o2;
        } else {
            const bfr* kp = Kg + (size_t)(b * TK + kt * 64 + srow) * kvstr + h * HD_ + ht * 16;
            *(bf16x8*)(Ks + srow * AST + ht * 16) = *(const bf16x8*)kp;
            *(bf16x8*)(Ks + srow * AST + ht * 16 + 8) = *(const bf16x8*)(kp + 8);
        }
        {
            const bfr* vp = Vg + (size_t)(b * TK + kt * 64 + srow) * kvstr + h * HD_ + ht * 16;
            bf16x8 v0 = *(const bf16x8*)vp;
            bf16x8 v1 = *(const bf16x8*)(vp + 8);
#pragma unroll
            for (int i = 0; i < 8; ++i) VTs[(ht * 16 + i) * AST + srow] = v0[i];
#pragma unroll
            for (int i = 0; i < 8; ++i) VTs[(ht * 16 + 8 + i) * AST + srow] = v1[i];
        }
        __syncthreads();

        f32x4 s[4] = {};
#pragma unroll
        for (int kk = 0; kk < 64; kk += 32) {
            bf16x8 a = *(const bf16x8*)(Qs + (w * 16 + l4) * AST + kk + hi4 * 8);
#pragma unroll
            for (int n = 0; n < 4; ++n) {
                bf16x8 bb = *(const bf16x8*)(Ks + (n * 16 + l4) * AST + kk + hi4 * 8);
                s[n] = __builtin_amdgcn_mfma_f32_16x16x32_bf16(a, bb, s[n], 0, 0, 0);
            }
        }
        float madd[4];
        if (!CAUSAL) {
#pragma unroll
            for (int n = 0; n < 4; ++n)
                madd[n] = pad[b * TK + kt * 64 + n * 16 + l4] ? -1e30f : 0.f;
        }
#pragma unroll
        for (int r = 0; r < 4; ++r) {
            int qrow = q0 + w * 16 + hi4 * 4 + r;
            float sv[4];
#pragma unroll
            for (int n = 0; n < 4; ++n) {
                float x = s[n][r] * 0.125f;
                if (CAUSAL) {
                    int col = kt * 64 + n * 16 + l4;
                    if (col > qrow) x = -1e30f;
                } else x += madd[n];
                sv[n] = x;
            }
            float mx = fmaxf(fmaxf(sv[0], sv[1]), fmaxf(sv[2], sv[3]));
#pragma unroll
            for (int off = 1; off < 16; off <<= 1) mx = fmaxf(mx, __shfl_xor(mx, off));
            float mnew = fmaxf(m_run[r], mx);
            float alpha = expf(m_run[r] - mnew);
            float pv[4], psum = 0.f;
#pragma unroll
            for (int n = 0; n < 4; ++n) { pv[n] = expf(sv[n] - mnew); psum += pv[n]; }
#pragma unroll
            for (int off = 1; off < 16; off <<= 1) psum += __shfl_xor(psum, off);
            l_run[r] = l_run[r] * alpha + psum;
            m_run[r] = mnew;
#pragma unroll
            for (int n = 0; n < 4; ++n) o_acc[n][r] *= alpha;
#pragma unroll
            for (int n = 0; n < 4; ++n)
                Ps[(w * 16 + hi4 * 4 + r) * AST + n * 16 + l4] = (bfr)pv[n];
        }
#pragma unroll
        for (int kk = 0; kk < 64; kk += 32) {
            bf16x8 pa = *(const bf16x8*)(Ps + (w * 16 + l4) * AST + kk + hi4 * 8);
#pragma unroll
            for (int n = 0; n < 4; ++n) {
                bf16x8 vb = *(const bf16x8*)(VTs + (n * 16 + l4) * AST + kk + hi4 * 8);
                o_acc[n] = __builtin_amdgcn_mfma_f32_16x16x32_bf16(pa, vb, o_acc[n], 0, 0, 0);
            }
        }
    }
#pragma unroll
    for (int r = 0; r < 4; ++r) {
        float inv = 1.0f / l_run[r];
        int qrow = q0 + w * 16 + hi4 * 4 + r;
#pragma unroll
        for (int n = 0; n < 4; ++n)
            Ohi[(size_t)(b * L_ + qrow) * D_ + h * HD_ + n * 16 + l4] = (bfr)(o_acc[n][r] * inv);
    }
}

__global__ void rope_tables_kernel(float* __restrict__ cosT, float* __restrict__ sinT)
{
    int gid = blockIdx.x * blockDim.x + threadIdx.x;
    if (gid >= L_ * 32) return;
    int l = gid >> 5, i = gid & 31;
    float inv = powf(10000.0f, -(float)(2 * i) / (float)HD_);
    float ang = (float)l * inv;
    cosT[gid] = cosf(ang);
    sinT[gid] = sinf(ang);
}

__global__ void embed_kernel(const int* __restrict__ targets, const float* __restrict__ emb,
                             float* __restrict__ tgt, bfr* __restrict__ thi)
{
    int gid = blockIdx.x * blockDim.x + threadIdx.x;
    if (gid >= B_ * L_ * D_) return;
    int d = gid & (D_ - 1);
    int r = gid >> 9;
    int tok = targets[r];
    float x = emb[(size_t)tok * D_ + d] * 22.62741699796952f;
    tgt[gid] = x;
    thi[gid] = (bfr)x;
}

__global__ void pad_kernel(const float* __restrict__ mem, int* __restrict__ pad)
{
    int gid = blockIdx.x * blockDim.x + threadIdx.x;
    if (gid >= B_ * T_) return;
    const float* p = mem + (size_t)gid * D_;
    float s = 0.f;
    for (int d = 0; d < D_; ++d) s += fabsf(p[d]);
    pad[gid] = (s == 0.0f) ? 1 : 0;
}

// y = LN(tgt + delta); y -> yout (f32) and thi (bf16); tgt read as residual.
__global__ __launch_bounds__(128) void ln_residual_kernel(
    const float* __restrict__ tgt, const float* __restrict__ delta,
    const float* __restrict__ g, const float* __restrict__ bb,
    float* __restrict__ yout, bfr* __restrict__ thi)
{
    const int row = blockIdx.x;
    const int t = threadIdx.x;
    __shared__ float rbuf[128];
    size_t base = (size_t)row * D_ + t * 4;
    float4 x = *(const float4*)(tgt + base);
    float4 dl = *(const float4*)(delta + base);
    x.x += dl.x; x.y += dl.y; x.z += dl.z; x.w += dl.w;
    rbuf[t] = x.x + x.y + x.z + x.w;
    __syncthreads();
    for (int off = 64; off > 0; off >>= 1) { if (t < off) rbuf[t] += rbuf[t + off]; __syncthreads(); }
    float mean = rbuf[0] * (1.0f / D_);
    __syncthreads();
    float4 d4 = {x.x - mean, x.y - mean, x.z - mean, x.w - mean};
    rbuf[t] = d4.x * d4.x + d4.y * d4.y + d4.z * d4.z + d4.w * d4.w;
    __syncthreads();
    for (int off = 64; off > 0; off >>= 1) { if (t < off) rbuf[t] += rbuf[t + off]; __syncthreads(); }
    float inv = 1.0f / sqrtf(rbuf[0] * (1.0f / D_) + 1e-5f);
    float4 g4 = *(const float4*)(g + t * 4);
    float4 b4 = *(const float4*)(bb + t * 4);
    float4 y = {d4.x * inv * g4.x + b4.x, d4.y * inv * g4.y + b4.y,
                d4.z * inv * g4.z + b4.z, d4.w * inv * g4.w + b4.w};
    *(float4*)(yout + base) = y;
    bf16x4 h4 = {(bfr)y.x, (bfr)y.y, (bfr)y.z, (bfr)y.w};
    *(bf16x4*)(thi + base) = h4;
}

__global__ void fillf_kernel(float* p, float v, size_t n)
{
    size_t gid = (size_t)blockIdx.x * 256 + threadIdx.x;
    if (gid < n) p[gid] = v;
}

extern "C" void kernel_launch(void* const* d_in, const int* in_sizes, int n_in,
                              void* d_out, int out_size, void* d_ws, size_t ws_size,
                              hipStream_t stream)
{
    const float* enc    = (const float*)d_in[0];
    const int*   tg     = (const int*)d_in[1];
    const float* emb    = (const float*)d_in[2];
    const float* inp_w  = (const float*)d_in[3];
    const float* inp_b  = (const float*)d_in[4];
    const float* out_w  = (const float*)d_in[5];
    const float* out_b  = (const float*)d_in[6];
    const float* qw     = (const float*)d_in[7];
    const float* qb     = (const float*)d_in[8];
    const float* kw     = (const float*)d_in[9];
    const float* kb     = (const float*)d_in[10];
    const float* vw     = (const float*)d_in[11];
    const float* vb     = (const float*)d_in[12];
    const float* ow     = (const float*)d_in[13];
    const float* ob     = (const float*)d_in[14];
    const float* mha_w  = (const float*)d_in[15];
    const float* mha_b  = (const float*)d_in[16];
    const float* mha_ow = (const float*)d_in[17];
    const float* mha_ob = (const float*)d_in[18];
    const float* w1     = (const float*)d_in[19];
    const float* b1     = (const float*)d_in[20];
    const float* w2     = (const float*)d_in[21];
    const float* b2     = (const float*)d_in[22];
    const float* ln1g   = (const float*)d_in[23];
    const float* ln1b   = (const float*)d_in[24];
    const float* ln2g   = (const float*)d_in[25];
    const float* ln2b   = (const float*)d_in[26];
    const float* ln3g   = (const float*)d_in[27];
    const float* ln3b   = (const float*)d_in[28];

    const int BL = B_ * L_;        // 4096
    const int BT = B_ * T_;        // 16384
    const size_t N_LOGITS = (size_t)BL * V_;
    const int D2 = D_ * D_;        // 262144

    const size_t WS_NEEDED =
        (size_t)BT * 1024 * sizeof(bfr)
        + (size_t)BL * D_ * sizeof(float)
        + (size_t)BL * D_ * sizeof(bfr)
        + (size_t)2 * L_ * 32 * sizeof(float) + (size_t)BT * sizeof(int)
        + (size_t)V_ * D_ * sizeof(bfr);
    if (ws_size < WS_NEEDED) {
        fillf_kernel<<<((size_t)out_size + 255) / 256, 256, 0, stream>>>((float*)d_out, 0.f, (size_t)out_size);
        return;
    }
    bfr*   f_KVb = (bfr*)d_ws;                          // [BT,1024]: K2 | V2
    float* f_tgt = (float*)(f_KVb + (size_t)BT * 1024);
    bfr*   tgt_hi = (bfr*)(f_tgt + (size_t)BL * D_);
    float* f_cos = (float*)(tgt_hi + (size_t)BL * D_);
    float* f_sin = f_cos + (size_t)L_ * 32;
    int*   f_pad = (int*)(f_sin + (size_t)L_ * 32);
    bfr*   ow_hi = (bfr*)(f_pad + BT);

    bfr* wp = (bfr*)d_out;
    bfr* qkvw_hi = wp;  wp += 3 * D2;
    bfr* inp_hi  = wp;  wp += D2;
    bfr* mha_hi  = wp;  wp += 3 * D2;
    bfr* o_hi    = wp;  wp += D2;
    bfr* mo_hi   = wp;  wp += D2;
    bfr* w1_hi   = wp;  wp += DFF_ * D_;
    bfr* w2_hi   = wp;  wp += D_ * DFF_;
    float* f_qkvb = (float*)wp;                 // [1536]
    float* lr    = f_qkvb + 3 * D_;
    float* f_t2  = lr;                                   // [BL,512] f32
    bfr*   qkv   = (bfr*)(f_t2 + (size_t)BL * D_);       // [BL,1536]
    bfr*   qcr   = qkv + (size_t)BL * 3 * D_;            // [BL,512]
    bfr*   t1_hi = qcr + (size_t)BL * D_;                // [BL,512]
    bfr*   ffh_hi = t1_hi + (size_t)BL * D_;             // [BL,1024]
    float* f_mem = lr;  // prologue-only alias (BT*D f32 = 33.5MB <= 46MB layer region)

    // single batched weight convert (bf16) + bias concat
    {
        ConvTable tab{};
        int blk = 0, ne = 0;
        auto add = [&](const float* s, bfr* d, int n) {
            tab.e[ne] = {s, d, n, blk};
            blk += (n + 255) >> 8;
            ++ne;
        };
        add(qw, qkvw_hi, D2);
        add(kw, qkvw_hi + D2, D2);
        add(vw, qkvw_hi + 2 * D2, D2);
        add(inp_w, inp_hi, D2);
        add(mha_w, mha_hi, 3 * D2);
        add(ow, o_hi, D2);
        add(mha_ow, mo_hi, D2);
        add(w1, w1_hi, DFF_ * D_);
        add(w2, w2_hi, D_ * DFF_);
        add(out_w, ow_hi, V_ * D_);
        tab.ne = ne;
        conv_many_kernel<<<blk, 256, 0, stream>>>(tab);
    }
    copy3_kernel<<<6, 256, 0, stream>>>(qb, kb, vb, f_qkvb);

    rope_tables_kernel<<<(L_ * 32 + 255) / 256, 256, 0, stream>>>(f_cos, f_sin);
    embed_kernel<<<(BL * D_ + 255) / 256, 256, 0, stream>>>(tg, emb, f_tgt, tgt_hi);

    // prologue: memory f32, pad mask, fused K2|V2 (bf16, N=1024)
    gemm_split<0><<<dim3(D_ / 64, BT / 128), 256, 0, stream>>>(enc, inp_hi, inp_b, f_mem, nullptr, BT, D_, INC_);
    pad_kernel<<<(BT + 255) / 256, 256, 0, stream>>>(f_mem, f_pad);
    gemm_split<1><<<dim3(1024 / 64, BT / 128), 256, 0, stream>>>(f_mem, mha_hi + (size_t)D2, mha_b + D_, nullptr, f_KVb, BT, 1024, D_);

    float* o_logits = (float*)d_out;
    float* o_tgt = o_logits + N_LOGITS;

    for (int layer = 0; layer < NL_; ++layer) {
        // self attention
        gemm_ps<0, 1, 64><<<(BL / 64) * (3 * D_ / 64), 256, 0, stream>>>(tgt_hi, qkvw_hi, f_qkvb, nullptr, qkv, BL, 3 * D_, D_);
        attn_kernel<L_, 1><<<B_ * H_ * 2, 256, 0, stream>>>(qkv, 3 * D_, qkv + D_, qkv + 2 * D_, 3 * D_, nullptr, f_cos, f_sin, t1_hi);
        gemm_ps<0, 0, 64><<<(BL / 64) * (D_ / 64), 256, 0, stream>>>(t1_hi, o_hi, ob, f_t2, nullptr, BL, D_, D_);
        ln_residual_kernel<<<BL, 128, 0, stream>>>(f_tgt, f_t2, ln1g, ln1b, f_tgt, tgt_hi);
        // cross attention
        gemm_ps<0, 1, 64><<<(BL / 64) * (D_ / 64), 256, 0, stream>>>(tgt_hi, mha_hi, mha_b, nullptr, qcr, BL, D_, D_);
        attn_kernel<T_, 0><<<B_ * H_ * 2, 256, 0, stream>>>(qcr, D_, f_KVb, f_KVb + D_, 1024, f_pad, nullptr, nullptr, t1_hi);
        gemm_ps<0, 0, 64><<<(BL / 64) * (D_ / 64), 256, 0, stream>>>(t1_hi, mo_hi, mha_ob, f_t2, nullptr, BL, D_, D_);
        ln_residual_kernel<<<BL, 128, 0, stream>>>(f_tgt, f_t2, ln2g, ln2b, f_tgt, tgt_hi);
        // FFN
        gemm_ps<1, 1, 64><<<(BL / 64) * (DFF_ / 64), 256, 0, stream>>>(tgt_hi, w1_hi, b1, nullptr, ffh_hi, BL, DFF_, D_);
        gemm_ps<0, 0, 64><<<(BL / 64) * (D_ / 64), 256, 0, stream>>>(ffh_hi, w2_hi, b2, f_t2, nullptr, BL, D_, DFF_);
        // last LN writes final tgt (f32) directly to output slot; earlier ones to f_tgt
        float* yout = (layer == NL_ - 1) ? o_tgt : f_tgt;
        ln_residual_kernel<<<BL, 128, 0, stream>>>(f_tgt, f_t2, ln3g, ln3b, yout, tgt_hi);
    }

    // all d_out scratch dead; logits f32
    gemm_ps<0, 0, 128><<<(BL / 128) * (V_ / 64), 256, 0, stream>>>(tgt_hi, ow_hi, out_b, o_logits, nullptr, BL, V_, D_);
}

// Round 17
// 1040.958 us; speedup vs baseline: 1.4475x; 1.0520x over previous
//
#include <hip/hip_runtime.h>
#include <hip/hip_bf16.h>

#define B_ 32
#define T_ 512
#define L_ 128
#define INC_ 512
#define D_ 512
#define H_ 8
#define HD_ 64
#define NL_ 6
#define DFF_ 1024
#define V_ 8000
#define LDSK 40  // gemm LDS row stride (bf16)
#define AST 72   // attn LDS row stride (bf16)

typedef __bf16 bfr;
typedef __attribute__((ext_vector_type(8))) __bf16 bf16x8;
typedef __attribute__((ext_vector_type(4))) __bf16 bf16x4;
typedef __attribute__((ext_vector_type(4))) float f32x4;

// ---- batched f32 -> bf16 convert ----
struct ConvDesc { const float* src; bfr* dst; int n; int blk0; };
struct ConvTable { ConvDesc e[12]; int ne; };

__global__ void conv_many_kernel(ConvTable tab)
{
    int b = blockIdx.x;
    for (int i = 0; i < tab.ne; ++i) {
        const ConvDesc d = tab.e[i];
        int nb = (d.n + 255) >> 8;
        if (b >= d.blk0 && b < d.blk0 + nb) {
            int g = (b - d.blk0) * 256 + threadIdx.x;
            if (g < d.n) d.dst[g] = (bfr)d.src[g];
            return;
        }
    }
}

__global__ void copy3_kernel(const float* a, const float* b, const float* c, float* dst)
{
    int g = blockIdx.x * 256 + threadIdx.x;
    if (g < D_) dst[g] = a[g];
    else if (g < 2 * D_) dst[g] = b[g - D_];
    else if (g < 3 * D_) dst[g] = c[g - 2 * D_];
}

// bijective XCD-chunk remap (m204) + GROUP_M tile raster -> (pm, pn)
__device__ __forceinline__ void tile_map(int bid, int nbm, int nbn, int& pm, int& pn)
{
    int nwg = nbm * nbn;
    int q = nwg >> 3, r = nwg & 7;
    int xcd = bid & 7, idx = bid >> 3;
    int wgid = (xcd < r ? xcd * (q + 1) : r * (q + 1) + (xcd - r) * q) + idx;
    const int GROUP = 8;
    int per_group = GROUP * nbn;
    int gid = wgid / per_group;
    int first = gid * GROUP;
    int gsz = min(nbm - first, GROUP);
    int rem = wgid - gid * per_group;
    pm = first + rem % gsz;
    pn = rem / gsz;
}

// ---- GEMM, A bf16, W bf16 (1-term). BM in {64,128}; 1D grid + swizzle ----
// OUT: 0=f32, 1=bf16
template <int ACT, int OUT, int BM>
__global__ __launch_bounds__(256, 2) void gemm_ps(
    const bfr* __restrict__ Ahi,
    const bfr* __restrict__ Whi,
    const float* __restrict__ bias, float* __restrict__ Cf,
    bfr* __restrict__ Chi, int M, int N, int K)
{
    constexpr int MF = BM / 32;
    __shared__ bfr Ah_s[BM * LDSK];
    __shared__ bfr Wh_s[64 * LDSK];
    const int t = threadIdx.x;
    int pm, pn;
    tile_map(blockIdx.x, M / BM, N / 64, pm, pn);
    const int bm = pm * BM, bn = pn * 64;
    const int w = t >> 6, lane = t & 63;
    const int wm = w >> 1, wn = w & 1;
    const int fr = lane & 15, kq = lane >> 4;
    const int wr = t >> 2, wk = (t & 3) * 8;

    f32x4 acc[MF][2] = {};

    for (int k0 = 0; k0 < K; k0 += 32) {
        if constexpr (BM == 128) {
            const int ar = t >> 1, ah = (t & 1) * 16;
            const bfr* ap = Ahi + (size_t)(bm + ar) * K + (k0 + ah);
            *(bf16x8*)(Ah_s + ar * LDSK + ah) = *(const bf16x8*)ap;
            *(bf16x8*)(Ah_s + ar * LDSK + ah + 8) = *(const bf16x8*)(ap + 8);
        } else {
            const int ar = t >> 2, ah = (t & 3) * 8;
            *(bf16x8*)(Ah_s + ar * LDSK + ah) = *(const bf16x8*)(Ahi + (size_t)(bm + ar) * K + (k0 + ah));
        }
        *(bf16x8*)(Wh_s + wr * LDSK + wk) = *(const bf16x8*)(Whi + (size_t)(bn + wr) * K + (k0 + wk));
        __syncthreads();
        bf16x8 Afh[MF], Wfh[2];
#pragma unroll
        for (int i = 0; i < MF; ++i)
            Afh[i] = *(const bf16x8*)(Ah_s + (wm * (BM / 2) + i * 16 + fr) * LDSK + kq * 8);
#pragma unroll
        for (int j = 0; j < 2; ++j)
            Wfh[j] = *(const bf16x8*)(Wh_s + (wn * 32 + j * 16 + fr) * LDSK + kq * 8);
#pragma unroll
        for (int i = 0; i < MF; ++i)
#pragma unroll
            for (int j = 0; j < 2; ++j)
                acc[i][j] = __builtin_amdgcn_mfma_f32_16x16x32_bf16(Afh[i], Wfh[j], acc[i][j], 0, 0, 0);
        __syncthreads();
    }
#pragma unroll
    for (int i = 0; i < MF; ++i) {
        int row0 = bm + wm * (BM / 2) + i * 16 + (lane >> 4) * 4;
#pragma unroll
        for (int j = 0; j < 2; ++j) {
            int col = bn + wn * 32 + j * 16 + fr;
            float bj = bias[col];
#pragma unroll
            for (int r = 0; r < 4; ++r) {
                float v = acc[i][j][r] + bj;
                if (ACT == 1) v = 0.5f * v * (1.0f + erff(v * 0.70710678118654752f));
                size_t idx = (size_t)(row0 + r) * N + col;
                if (OUT == 0) Cf[idx] = v;
                else Chi[idx] = (bfr)v;
            }
        }
    }
}

// ---- wide-Q fused flash attention: one block per (b,h), 8 waves x 16 q rows ----
// K staged by threads 0..255, V (transposed) by 256..511. RoPE folded when CAUSAL.
template <int TK, int CAUSAL>
__global__ __launch_bounds__(512) void attn_wide(
    const bfr* __restrict__ Qg, int qstr,
    const bfr* __restrict__ Kg, const bfr* __restrict__ Vg, int kvstr,
    const int* __restrict__ pad,
    const float* __restrict__ cosT, const float* __restrict__ sinT,
    bfr* __restrict__ Ohi)
{
    __shared__ bfr Qs[128 * AST];
    __shared__ bfr Ks[64 * AST];
    __shared__ bfr VTs[64 * AST];
    __shared__ bfr Ps[128 * AST];
    const int bh = blockIdx.x;
    const int h = bh & 7, b = bh >> 3;
    const int t = threadIdx.x;
    const int w = t >> 6, lane = t & 63;
    const int l4 = lane & 15, hi4 = lane >> 4;
    const int qr0 = w * 16;

    // stage Q: 128 rows, 4 threads/row
    {
        const int srow = t >> 2, ht = t & 3;
        if (CAUSAL) {
            const bfr* qp = Qg + (size_t)(b * L_ + srow) * qstr + h * HD_ + ht * 8;
            bf16x8 a = *(const bf16x8*)qp;
            bf16x8 bb = *(const bf16x8*)(qp + 32);
            bf16x8 o1, o2;
#pragma unroll
            for (int j = 0; j < 8; ++j) {
                float c = cosT[srow * 32 + ht * 8 + j], s = sinT[srow * 32 + ht * 8 + j];
                float x1 = (float)a[j], x2 = (float)bb[j];
                o1[j] = (bfr)(x1 * c - x2 * s);
                o2[j] = (bfr)(x2 * c + x1 * s);
            }
            *(bf16x8*)(Qs + srow * AST + ht * 8) = o1;
            *(bf16x8*)(Qs + srow * AST + ht * 8 + 32) = o2;
        } else {
            const bfr* qp = Qg + (size_t)(b * L_ + srow) * qstr + h * HD_ + ht * 16;
            *(bf16x8*)(Qs + srow * AST + ht * 16) = *(const bf16x8*)qp;
            *(bf16x8*)(Qs + srow * AST + ht * 16 + 8) = *(const bf16x8*)(qp + 8);
        }
    }

    f32x4 o_acc[4] = {};
    float m_run[4], l_run[4];
#pragma unroll
    for (int r = 0; r < 4; ++r) { m_run[r] = -1e30f; l_run[r] = 0.f; }

    for (int kt = 0; kt < TK / 64; ++kt) {
        __syncthreads();  // prior-iter LDS reads done (covers Q stage on iter 0)
        if (t < 256) {    // stage K tile (64 rows, 4 threads/row)
            const int srow = t >> 2, ht = t & 3;
            int krow = kt * 64 + srow;
            if (CAUSAL) {
                const bfr* kp = Kg + (size_t)(b * TK + krow) * kvstr + h * HD_ + ht * 8;
                bf16x8 a = *(const bf16x8*)kp;
                bf16x8 bb = *(const bf16x8*)(kp + 32);
                bf16x8 o1, o2;
#pragma unroll
                for (int j = 0; j < 8; ++j) {
                    float c = cosT[krow * 32 + ht * 8 + j], s = sinT[krow * 32 + ht * 8 + j];
                    float x1 = (float)a[j], x2 = (float)bb[j];
                    o1[j] = (bfr)(x1 * c - x2 * s);
                    o2[j] = (bfr)(x2 * c + x1 * s);
                }
                *(bf16x8*)(Ks + srow * AST + ht * 8) = o1;
                *(bf16x8*)(Ks + srow * AST + ht * 8 + 32) = o2;
            } else {
                const bfr* kp = Kg + (size_t)(b * TK + krow) * kvstr + h * HD_ + ht * 16;
                *(bf16x8*)(Ks + srow * AST + ht * 16) = *(const bf16x8*)kp;
                *(bf16x8*)(Ks + srow * AST + ht * 16 + 8) = *(const bf16x8*)(kp + 8);
            }
        } else {          // stage V tile transposed (64 rows, 4 threads/row)
            const int tt = t - 256;
            const int srow = tt >> 2, ht = tt & 3;
            const bfr* vp = Vg + (size_t)(b * TK + kt * 64 + srow) * kvstr + h * HD_ + ht * 16;
            bf16x8 v0 = *(const bf16x8*)vp;
            bf16x8 v1 = *(const bf16x8*)(vp + 8);
#pragma unroll
            for (int i = 0; i < 8; ++i) VTs[(ht * 16 + i) * AST + srow] = v0[i];
#pragma unroll
            for (int i = 0; i < 8; ++i) VTs[(ht * 16 + 8 + i) * AST + srow] = v1[i];
        }
        __syncthreads();

        f32x4 s[4] = {};
#pragma unroll
        for (int kk = 0; kk < 64; kk += 32) {
            bf16x8 a = *(const bf16x8*)(Qs + (qr0 + l4) * AST + kk + hi4 * 8);
#pragma unroll
            for (int n = 0; n < 4; ++n) {
                bf16x8 bb = *(const bf16x8*)(Ks + (n * 16 + l4) * AST + kk + hi4 * 8);
                s[n] = __builtin_amdgcn_mfma_f32_16x16x32_bf16(a, bb, s[n], 0, 0, 0);
            }
        }
        float madd[4];
        if (!CAUSAL) {
#pragma unroll
            for (int n = 0; n < 4; ++n)
                madd[n] = pad[b * TK + kt * 64 + n * 16 + l4] ? -1e30f : 0.f;
        }
#pragma unroll
        for (int r = 0; r < 4; ++r) {
            int qrow = qr0 + hi4 * 4 + r;
            float sv[4];
#pragma unroll
            for (int n = 0; n < 4; ++n) {
                float x = s[n][r] * 0.125f;
                if (CAUSAL) {
                    int col = kt * 64 + n * 16 + l4;
                    if (col > qrow) x = -1e30f;
                } else x += madd[n];
                sv[n] = x;
            }
            float mx = fmaxf(fmaxf(sv[0], sv[1]), fmaxf(sv[2], sv[3]));
#pragma unroll
            for (int off = 1; off < 16; off <<= 1) mx = fmaxf(mx, __shfl_xor(mx, off));
            float mnew = fmaxf(m_run[r], mx);
            float alpha = expf(m_run[r] - mnew);
            float pv[4], psum = 0.f;
#pragma unroll
            for (int n = 0; n < 4; ++n) { pv[n] = expf(sv[n] - mnew); psum += pv[n]; }
#pragma unroll
            for (int off = 1; off < 16; off <<= 1) psum += __shfl_xor(psum, off);
            l_run[r] = l_run[r] * alpha + psum;
            m_run[r] = mnew;
#pragma unroll
            for (int n = 0; n < 4; ++n) o_acc[n][r] *= alpha;
#pragma unroll
            for (int n = 0; n < 4; ++n)
                Ps[(qr0 + hi4 * 4 + r) * AST + n * 16 + l4] = (bfr)pv[n];
        }
#pragma unroll
        for (int kk = 0; kk < 64; kk += 32) {
            bf16x8 pa = *(const bf16x8*)(Ps + (qr0 + l4) * AST + kk + hi4 * 8);
#pragma unroll
            for (int n = 0; n < 4; ++n) {
                bf16x8 vb = *(const bf16x8*)(VTs + (n * 16 + l4) * AST + kk + hi4 * 8);
                o_acc[n] = __builtin_amdgcn_mfma_f32_16x16x32_bf16(pa, vb, o_acc[n], 0, 0, 0);
            }
        }
    }
#pragma unroll
    for (int r = 0; r < 4; ++r) {
        float inv = 1.0f / l_run[r];
        int qrow = qr0 + hi4 * 4 + r;
#pragma unroll
        for (int n = 0; n < 4; ++n)
            Ohi[(size_t)(b * L_ + qrow) * D_ + h * HD_ + n * 16 + l4] = (bfr)(o_acc[n][r] * inv);
    }
}

__global__ void rope_tables_kernel(float* __restrict__ cosT, float* __restrict__ sinT)
{
    int gid = blockIdx.x * blockDim.x + threadIdx.x;
    if (gid >= L_ * 32) return;
    int l = gid >> 5, i = gid & 31;
    float inv = powf(10000.0f, -(float)(2 * i) / (float)HD_);
    float ang = (float)l * inv;
    cosT[gid] = cosf(ang);
    sinT[gid] = sinf(ang);
}

__global__ void embed_kernel(const int* __restrict__ targets, const float* __restrict__ emb,
                             float* __restrict__ tgt, bfr* __restrict__ thi)
{
    int gid = blockIdx.x * blockDim.x + threadIdx.x;
    if (gid >= B_ * L_ * D_) return;
    int d = gid & (D_ - 1);
    int r = gid >> 9;
    int tok = targets[r];
    float x = emb[(size_t)tok * D_ + d] * 22.62741699796952f;
    tgt[gid] = x;
    thi[gid] = (bfr)x;
}

// pad mask from bf16 memory rows
__global__ void pad_kernel(const bfr* __restrict__ mem, int* __restrict__ pad)
{
    int gid = blockIdx.x * blockDim.x + threadIdx.x;
    if (gid >= B_ * T_) return;
    const bfr* p = mem + (size_t)gid * D_;
    float s = 0.f;
    for (int d0 = 0; d0 < D_; d0 += 8) {
        bf16x8 v = *(const bf16x8*)(p + d0);
#pragma unroll
        for (int j = 0; j < 8; ++j) s += fabsf((float)v[j]);
    }
    pad[gid] = (s == 0.0f) ? 1 : 0;
}

// y = LN(tgt + delta); y -> yout (f32) and thi (bf16)
__global__ __launch_bounds__(128) void ln_residual_kernel(
    const float* __restrict__ tgt, const float* __restrict__ delta,
    const float* __restrict__ g, const float* __restrict__ bb,
    float* __restrict__ yout, bfr* __restrict__ thi)
{
    const int row = blockIdx.x;
    const int t = threadIdx.x;
    __shared__ float rbuf[128];
    size_t base = (size_t)row * D_ + t * 4;
    float4 x = *(const float4*)(tgt + base);
    float4 dl = *(const float4*)(delta + base);
    x.x += dl.x; x.y += dl.y; x.z += dl.z; x.w += dl.w;
    rbuf[t] = x.x + x.y + x.z + x.w;
    __syncthreads();
    for (int off = 64; off > 0; off >>= 1) { if (t < off) rbuf[t] += rbuf[t + off]; __syncthreads(); }
    float mean = rbuf[0] * (1.0f / D_);
    __syncthreads();
    float4 d4 = {x.x - mean, x.y - mean, x.z - mean, x.w - mean};
    rbuf[t] = d4.x * d4.x + d4.y * d4.y + d4.z * d4.z + d4.w * d4.w;
    __syncthreads();
    for (int off = 64; off > 0; off >>= 1) { if (t < off) rbuf[t] += rbuf[t + off]; __syncthreads(); }
    float inv = 1.0f / sqrtf(rbuf[0] * (1.0f / D_) + 1e-5f);
    float4 g4 = *(const float4*)(g + t * 4);
    float4 b4 = *(const float4*)(bb + t * 4);
    float4 y = {d4.x * inv * g4.x + b4.x, d4.y * inv * g4.y + b4.y,
                d4.z * inv * g4.z + b4.z, d4.w * inv * g4.w + b4.w};
    *(float4*)(yout + base) = y;
    bf16x4 h4 = {(bfr)y.x, (bfr)y.y, (bfr)y.z, (bfr)y.w};
    *(bf16x4*)(thi + base) = h4;
}

__global__ void fillf_kernel(float* p, float v, size_t n)
{
    size_t gid = (size_t)blockIdx.x * 256 + threadIdx.x;
    if (gid < n) p[gid] = v;
}

extern "C" void kernel_launch(void* const* d_in, const int* in_sizes, int n_in,
                              void* d_out, int out_size, void* d_ws, size_t ws_size,
                              hipStream_t stream)
{
    const float* enc    = (const float*)d_in[0];
    const int*   tg     = (const int*)d_in[1];
    const float* emb    = (const float*)d_in[2];
    const float* inp_w  = (const float*)d_in[3];
    const float* inp_b  = (const float*)d_in[4];
    const float* out_w  = (const float*)d_in[5];
    const float* out_b  = (const float*)d_in[6];
    const float* qw     = (const float*)d_in[7];
    const float* qb     = (const float*)d_in[8];
    const float* kw     = (const float*)d_in[9];
    const float* kb     = (const float*)d_in[10];
    const float* vw     = (const float*)d_in[11];
    const float* vb     = (const float*)d_in[12];
    const float* ow     = (const float*)d_in[13];
    const float* ob     = (const float*)d_in[14];
    const float* mha_w  = (const float*)d_in[15];
    const float* mha_b  = (const float*)d_in[16];
    const float* mha_ow = (const float*)d_in[17];
    const float* mha_ob = (const float*)d_in[18];
    const float* w1     = (const float*)d_in[19];
    const float* b1     = (const float*)d_in[20];
    const float* w2     = (const float*)d_in[21];
    const float* b2     = (const float*)d_in[22];
    const float* ln1g   = (const float*)d_in[23];
    const float* ln1b   = (const float*)d_in[24];
    const float* ln2g   = (const float*)d_in[25];
    const float* ln2b   = (const float*)d_in[26];
    const float* ln3g   = (const float*)d_in[27];
    const float* ln3b   = (const float*)d_in[28];

    const int BL = B_ * L_;        // 4096
    const int BT = B_ * T_;        // 16384
    const size_t N_LOGITS = (size_t)BL * V_;
    const int D2 = D_ * D_;        // 262144

    const size_t WS_NEEDED =
        (size_t)BT * 1024 * sizeof(bfr)
        + (size_t)BL * D_ * sizeof(float)
        + (size_t)BL * D_ * sizeof(bfr)
        + (size_t)2 * L_ * 32 * sizeof(float) + (size_t)BT * sizeof(int)
        + (size_t)V_ * D_ * sizeof(bfr);
    if (ws_size < WS_NEEDED) {
        fillf_kernel<<<((size_t)out_size + 255) / 256, 256, 0, stream>>>((float*)d_out, 0.f, (size_t)out_size);
        return;
    }
    bfr*   f_KVb = (bfr*)d_ws;                          // [BT,1024]: K2 | V2
    float* f_tgt = (float*)(f_KVb + (size_t)BT * 1024);
    bfr*   tgt_hi = (bfr*)(f_tgt + (size_t)BL * D_);
    float* f_cos = (float*)(tgt_hi + (size_t)BL * D_);
    float* f_sin = f_cos + (size_t)L_ * 32;
    int*   f_pad = (int*)(f_sin + (size_t)L_ * 32);
    bfr*   ow_hi = (bfr*)(f_pad + BT);

    bfr* wp = (bfr*)d_out;
    bfr* qkvw_hi = wp;  wp += 3 * D2;
    bfr* inp_hi  = wp;  wp += D2;
    bfr* mha_hi  = wp;  wp += 3 * D2;
    bfr* o_hi    = wp;  wp += D2;
    bfr* mo_hi   = wp;  wp += D2;
    bfr* w1_hi   = wp;  wp += DFF_ * D_;
    bfr* w2_hi   = wp;  wp += D_ * DFF_;
    float* f_qkvb = (float*)wp;                 // [1536]
    float* lr    = f_qkvb + 3 * D_;
    float* f_t2  = lr;                                   // [BL,512] f32
    bfr*   qkv   = (bfr*)(f_t2 + (size_t)BL * D_);       // [BL,1536]
    bfr*   qcr   = qkv + (size_t)BL * 3 * D_;            // [BL,512]
    bfr*   t1_hi = qcr + (size_t)BL * D_;                // [BL,512]
    bfr*   ffh_hi = t1_hi + (size_t)BL * D_;             // [BL,1024]
    // prologue-only aliases in the layer region (dead before layer loop):
    bfr*   enc_hi = (bfr*)lr;                            // [BT,512] bf16 = 16.8MB
    bfr*   mem_hi = enc_hi + (size_t)BT * D_;            // [BT,512] bf16 = 16.8MB (total 33.6 < 37.8MB)

    // single batched weight + enc convert (bf16) + bias concat
    {
        ConvTable tab{};
        int blk = 0, ne = 0;
        auto add = [&](const float* s, bfr* d, int n) {
            tab.e[ne] = {s, d, n, blk};
            blk += (n + 255) >> 8;
            ++ne;
        };
        add(qw, qkvw_hi, D2);
        add(kw, qkvw_hi + D2, D2);
        add(vw, qkvw_hi + 2 * D2, D2);
        add(inp_w, inp_hi, D2);
        add(mha_w, mha_hi, 3 * D2);
        add(ow, o_hi, D2);
        add(mha_ow, mo_hi, D2);
        add(w1, w1_hi, DFF_ * D_);
        add(w2, w2_hi, D_ * DFF_);
        add(out_w, ow_hi, V_ * D_);
        add(enc, enc_hi, BT * D_);
        tab.ne = ne;
        conv_many_kernel<<<blk, 256, 0, stream>>>(tab);
    }
    copy3_kernel<<<6, 256, 0, stream>>>(qb, kb, vb, f_qkvb);

    rope_tables_kernel<<<(L_ * 32 + 255) / 256, 256, 0, stream>>>(f_cos, f_sin);
    embed_kernel<<<(BL * D_ + 255) / 256, 256, 0, stream>>>(tg, emb, f_tgt, tgt_hi);

    // prologue (all bf16): memory, pad mask, fused K2|V2
    gemm_ps<0, 1, 128><<<(BT / 128) * (D_ / 64), 256, 0, stream>>>(enc_hi, inp_hi, inp_b, nullptr, mem_hi, BT, D_, INC_);
    pad_kernel<<<(BT + 255) / 256, 256, 0, stream>>>(mem_hi, f_pad);
    gemm_ps<0, 1, 128><<<(BT / 128) * (1024 / 64), 256, 0, stream>>>(mem_hi, mha_hi + (size_t)D2, mha_b + D_, nullptr, f_KVb, BT, 1024, D_);

    float* o_logits = (float*)d_out;
    float* o_tgt = o_logits + N_LOGITS;

    for (int layer = 0; layer < NL_; ++layer) {
        // self attention
        gemm_ps<0, 1, 64><<<(BL / 64) * (3 * D_ / 64), 256, 0, stream>>>(tgt_hi, qkvw_hi, f_qkvb, nullptr, qkv, BL, 3 * D_, D_);
        attn_wide<L_, 1><<<B_ * H_, 512, 0, stream>>>(qkv, 3 * D_, qkv + D_, qkv + 2 * D_, 3 * D_, nullptr, f_cos, f_sin, t1_hi);
        gemm_ps<0, 0, 64><<<(BL / 64) * (D_ / 64), 256, 0, stream>>>(t1_hi, o_hi, ob, f_t2, nullptr, BL, D_, D_);
        ln_residual_kernel<<<BL, 128, 0, stream>>>(f_tgt, f_t2, ln1g, ln1b, f_tgt, tgt_hi);
        // cross attention
        gemm_ps<0, 1, 64><<<(BL / 64) * (D_ / 64), 256, 0, stream>>>(tgt_hi, mha_hi, mha_b, nullptr, qcr, BL, D_, D_);
        attn_wide<T_, 0><<<B_ * H_, 512, 0, stream>>>(qcr, D_, f_KVb, f_KVb + D_, 1024, f_pad, nullptr, nullptr, t1_hi);
        gemm_ps<0, 0, 64><<<(BL / 64) * (D_ / 64), 256, 0, stream>>>(t1_hi, mo_hi, mha_ob, f_t2, nullptr, BL, D_, D_);
        ln_residual_kernel<<<BL, 128, 0, stream>>>(f_tgt, f_t2, ln2g, ln2b, f_tgt, tgt_hi);
        // FFN
        gemm_ps<1, 1, 64><<<(BL / 64) * (DFF_ / 64), 256, 0, stream>>>(tgt_hi, w1_hi, b1, nullptr, ffh_hi, BL, DFF_, D_);
        gemm_ps<0, 0, 64><<<(BL / 64) * (D_ / 64), 256, 0, stream>>>(ffh_hi, w2_hi, b2, f_t2, nullptr, BL, D_, DFF_);
        float* yout = (layer == NL_ - 1) ? o_tgt : f_tgt;
        ln_residual_kernel<<<BL, 128, 0, stream>>>(f_tgt, f_t2, ln3g, ln3b, yout, tgt_hi);
    }

    // all d_out scratch dead; logits f32
    gemm_ps<0, 0, 128><<<(BL / 128) * (V_ / 64), 256, 0, stream>>>(tgt_hi, ow_hi, out_b, o_logits, nullptr, BL, V_, D_);
}

// Round 18
// 967.630 us; speedup vs baseline: 1.5572x; 1.0758x over previous
//
#include <hip/hip_runtime.h>
#include <hip/hip_bf16.h>

#define B_ 32
#define T_ 512
#define L_ 128
#define INC_ 512
#define D_ 512
#define H_ 8
#define HD_ 64
#define NL_ 6
#define DFF_ 1024
#define V_ 8000
#define LDSK 40  // gemm LDS row stride (bf16)
#define AST 72   // attn LDS row stride (bf16)

typedef __bf16 bfr;
typedef __attribute__((ext_vector_type(8))) __bf16 bf16x8;
typedef __attribute__((ext_vector_type(4))) __bf16 bf16x4;
typedef __attribute__((ext_vector_type(4))) float f32x4;

// ---- batched f32 -> bf16 convert, 8 elems/thread (vectorized) ----
struct ConvDesc { const float* src; bfr* dst; int n; int blk0; };
struct ConvTable { ConvDesc e[12]; int ne; };

__global__ void conv_many_kernel(ConvTable tab)
{
    int b = blockIdx.x;
    for (int i = 0; i < tab.ne; ++i) {
        const ConvDesc d = tab.e[i];
        int nb = d.n >> 11;  // n / 2048 (all sizes divisible by 2048)
        if (b >= d.blk0 && b < d.blk0 + nb) {
            int g = ((b - d.blk0) * 256 + threadIdx.x) * 8;
            float4 v0 = *(const float4*)(d.src + g);
            float4 v1 = *(const float4*)(d.src + g + 4);
            bf16x8 o;
            o[0] = (bfr)v0.x; o[1] = (bfr)v0.y; o[2] = (bfr)v0.z; o[3] = (bfr)v0.w;
            o[4] = (bfr)v1.x; o[5] = (bfr)v1.y; o[6] = (bfr)v1.z; o[7] = (bfr)v1.w;
            *(bf16x8*)(d.dst + g) = o;
            return;
        }
    }
}

__global__ void copy3_kernel(const float* a, const float* b, const float* c, float* dst)
{
    int g = blockIdx.x * 256 + threadIdx.x;
    if (g < D_) dst[g] = a[g];
    else if (g < 2 * D_) dst[g] = b[g - D_];
    else if (g < 3 * D_) dst[g] = c[g - 2 * D_];
}

// bijective XCD-chunk remap (m204) + GROUP_M tile raster -> (pm, pn)
__device__ __forceinline__ void tile_map(int bid, int nbm, int nbn, int& pm, int& pn)
{
    int nwg = nbm * nbn;
    int q = nwg >> 3, r = nwg & 7;
    int xcd = bid & 7, idx = bid >> 3;
    int wgid = (xcd < r ? xcd * (q + 1) : r * (q + 1) + (xcd - r) * q) + idx;
    const int GROUP = 8;
    int per_group = GROUP * nbn;
    int gid = wgid / per_group;
    int first = gid * GROUP;
    int gsz = min(nbm - first, GROUP);
    int rem = wgid - gid * per_group;
    pm = first + rem % gsz;
    pn = rem / gsz;
}

// ---- GEMM, A bf16, W bf16 (1-term). BM in {64,128}; 1D grid + swizzle ----
// OUT: 0=f32, 1=bf16
template <int ACT, int OUT, int BM>
__global__ __launch_bounds__(256, 2) void gemm_ps(
    const bfr* __restrict__ Ahi,
    const bfr* __restrict__ Whi,
    const float* __restrict__ bias, float* __restrict__ Cf,
    bfr* __restrict__ Chi, int M, int N, int K)
{
    constexpr int MF = BM / 32;
    __shared__ bfr Ah_s[BM * LDSK];
    __shared__ bfr Wh_s[64 * LDSK];
    const int t = threadIdx.x;
    int pm, pn;
    tile_map(blockIdx.x, M / BM, N / 64, pm, pn);
    const int bm = pm * BM, bn = pn * 64;
    const int w = t >> 6, lane = t & 63;
    const int wm = w >> 1, wn = w & 1;
    const int fr = lane & 15, kq = lane >> 4;
    const int wr = t >> 2, wk = (t & 3) * 8;

    f32x4 acc[MF][2] = {};

    for (int k0 = 0; k0 < K; k0 += 32) {
        if constexpr (BM == 128) {
            const int ar = t >> 1, ah = (t & 1) * 16;
            const bfr* ap = Ahi + (size_t)(bm + ar) * K + (k0 + ah);
            *(bf16x8*)(Ah_s + ar * LDSK + ah) = *(const bf16x8*)ap;
            *(bf16x8*)(Ah_s + ar * LDSK + ah + 8) = *(const bf16x8*)(ap + 8);
        } else {
            const int ar = t >> 2, ah = (t & 3) * 8;
            *(bf16x8*)(Ah_s + ar * LDSK + ah) = *(const bf16x8*)(Ahi + (size_t)(bm + ar) * K + (k0 + ah));
        }
        *(bf16x8*)(Wh_s + wr * LDSK + wk) = *(const bf16x8*)(Whi + (size_t)(bn + wr) * K + (k0 + wk));
        __syncthreads();
        bf16x8 Afh[MF], Wfh[2];
#pragma unroll
        for (int i = 0; i < MF; ++i)
            Afh[i] = *(const bf16x8*)(Ah_s + (wm * (BM / 2) + i * 16 + fr) * LDSK + kq * 8);
#pragma unroll
        for (int j = 0; j < 2; ++j)
            Wfh[j] = *(const bf16x8*)(Wh_s + (wn * 32 + j * 16 + fr) * LDSK + kq * 8);
#pragma unroll
        for (int i = 0; i < MF; ++i)
#pragma unroll
            for (int j = 0; j < 2; ++j)
                acc[i][j] = __builtin_amdgcn_mfma_f32_16x16x32_bf16(Afh[i], Wfh[j], acc[i][j], 0, 0, 0);
        __syncthreads();
    }
#pragma unroll
    for (int i = 0; i < MF; ++i) {
        int row0 = bm + wm * (BM / 2) + i * 16 + (lane >> 4) * 4;
#pragma unroll
        for (int j = 0; j < 2; ++j) {
            int col = bn + wn * 32 + j * 16 + fr;
            float bj = bias[col];
#pragma unroll
            for (int r = 0; r < 4; ++r) {
                float v = acc[i][j][r] + bj;
                if (ACT == 1) v = 0.5f * v * (1.0f + erff(v * 0.70710678118654752f));
                size_t idx = (size_t)(row0 + r) * N + col;
                if (OUT == 0) Cf[idx] = v;
                else Chi[idx] = (bfr)v;
            }
        }
    }
}

// ---- wide-Q fused flash attention: one block per (b,h), 8 waves x 16 q rows ----
template <int TK, int CAUSAL>
__global__ __launch_bounds__(512) void attn_wide(
    const bfr* __restrict__ Qg, int qstr,
    const bfr* __restrict__ Kg, const bfr* __restrict__ Vg, int kvstr,
    const int* __restrict__ pad,
    const float* __restrict__ cosT, const float* __restrict__ sinT,
    bfr* __restrict__ Ohi)
{
    __shared__ bfr Qs[128 * AST];
    __shared__ bfr Ks[64 * AST];
    __shared__ bfr VTs[64 * AST];
    __shared__ bfr Ps[128 * AST];
    const int bh = blockIdx.x;
    const int h = bh & 7, b = bh >> 3;
    const int t = threadIdx.x;
    const int w = t >> 6, lane = t & 63;
    const int l4 = lane & 15, hi4 = lane >> 4;
    const int qr0 = w * 16;

    {
        const int srow = t >> 2, ht = t & 3;
        if (CAUSAL) {
            const bfr* qp = Qg + (size_t)(b * L_ + srow) * qstr + h * HD_ + ht * 8;
            bf16x8 a = *(const bf16x8*)qp;
            bf16x8 bb = *(const bf16x8*)(qp + 32);
            bf16x8 o1, o2;
#pragma unroll
            for (int j = 0; j < 8; ++j) {
                float c = cosT[srow * 32 + ht * 8 + j], s = sinT[srow * 32 + ht * 8 + j];
                float x1 = (float)a[j], x2 = (float)bb[j];
                o1[j] = (bfr)(x1 * c - x2 * s);
                o2[j] = (bfr)(x2 * c + x1 * s);
            }
            *(bf16x8*)(Qs + srow * AST + ht * 8) = o1;
            *(bf16x8*)(Qs + srow * AST + ht * 8 + 32) = o2;
        } else {
            const bfr* qp = Qg + (size_t)(b * L_ + srow) * qstr + h * HD_ + ht * 16;
            *(bf16x8*)(Qs + srow * AST + ht * 16) = *(const bf16x8*)qp;
            *(bf16x8*)(Qs + srow * AST + ht * 16 + 8) = *(const bf16x8*)(qp + 8);
        }
    }

    f32x4 o_acc[4] = {};
    float m_run[4], l_run[4];
#pragma unroll
    for (int r = 0; r < 4; ++r) { m_run[r] = -1e30f; l_run[r] = 0.f; }

    for (int kt = 0; kt < TK / 64; ++kt) {
        __syncthreads();
        if (t < 256) {
            const int srow = t >> 2, ht = t & 3;
            int krow = kt * 64 + srow;
            if (CAUSAL) {
                const bfr* kp = Kg + (size_t)(b * TK + krow) * kvstr + h * HD_ + ht * 8;
                bf16x8 a = *(const bf16x8*)kp;
                bf16x8 bb = *(const bf16x8*)(kp + 32);
                bf16x8 o1, o2;
#pragma unroll
                for (int j = 0; j < 8; ++j) {
                    float c = cosT[krow * 32 + ht * 8 + j], s = sinT[krow * 32 + ht * 8 + j];
                    float x1 = (float)a[j], x2 = (float)bb[j];
                    o1[j] = (bfr)(x1 * c - x2 * s);
                    o2[j] = (bfr)(x2 * c + x1 * s);
                }
                *(bf16x8*)(Ks + srow * AST + ht * 8) = o1;
                *(bf16x8*)(Ks + srow * AST + ht * 8 + 32) = o2;
            } else {
                const bfr* kp = Kg + (size_t)(b * TK + krow) * kvstr + h * HD_ + ht * 16;
                *(bf16x8*)(Ks + srow * AST + ht * 16) = *(const bf16x8*)kp;
                *(bf16x8*)(Ks + srow * AST + ht * 16 + 8) = *(const bf16x8*)(kp + 8);
            }
        } else {
            const int tt = t - 256;
            const int srow = tt >> 2, ht = tt & 3;
            const bfr* vp = Vg + (size_t)(b * TK + kt * 64 + srow) * kvstr + h * HD_ + ht * 16;
            bf16x8 v0 = *(const bf16x8*)vp;
            bf16x8 v1 = *(const bf16x8*)(vp + 8);
#pragma unroll
            for (int i = 0; i < 8; ++i) VTs[(ht * 16 + i) * AST + srow] = v0[i];
#pragma unroll
            for (int i = 0; i < 8; ++i) VTs[(ht * 16 + 8 + i) * AST + srow] = v1[i];
        }
        __syncthreads();

        f32x4 s[4] = {};
#pragma unroll
        for (int kk = 0; kk < 64; kk += 32) {
            bf16x8 a = *(const bf16x8*)(Qs + (qr0 + l4) * AST + kk + hi4 * 8);
#pragma unroll
            for (int n = 0; n < 4; ++n) {
                bf16x8 bb = *(const bf16x8*)(Ks + (n * 16 + l4) * AST + kk + hi4 * 8);
                s[n] = __builtin_amdgcn_mfma_f32_16x16x32_bf16(a, bb, s[n], 0, 0, 0);
            }
        }
        float madd[4];
        if (!CAUSAL) {
#pragma unroll
            for (int n = 0; n < 4; ++n)
                madd[n] = pad[b * TK + kt * 64 + n * 16 + l4] ? -1e30f : 0.f;
        }
#pragma unroll
        for (int r = 0; r < 4; ++r) {
            int qrow = qr0 + hi4 * 4 + r;
            float sv[4];
#pragma unroll
            for (int n = 0; n < 4; ++n) {
                float x = s[n][r] * 0.125f;
                if (CAUSAL) {
                    int col = kt * 64 + n * 16 + l4;
                    if (col > qrow) x = -1e30f;
                } else x += madd[n];
                sv[n] = x;
            }
            float mx = fmaxf(fmaxf(sv[0], sv[1]), fmaxf(sv[2], sv[3]));
#pragma unroll
            for (int off = 1; off < 16; off <<= 1) mx = fmaxf(mx, __shfl_xor(mx, off));
            float mnew = fmaxf(m_run[r], mx);
            float alpha = expf(m_run[r] - mnew);
            float pv[4], psum = 0.f;
#pragma unroll
            for (int n = 0; n < 4; ++n) { pv[n] = expf(sv[n] - mnew); psum += pv[n]; }
#pragma unroll
            for (int off = 1; off < 16; off <<= 1) psum += __shfl_xor(psum, off);
            l_run[r] = l_run[r] * alpha + psum;
            m_run[r] = mnew;
#pragma unroll
            for (int n = 0; n < 4; ++n) o_acc[n][r] *= alpha;
#pragma unroll
            for (int n = 0; n < 4; ++n)
                Ps[(qr0 + hi4 * 4 + r) * AST + n * 16 + l4] = (bfr)pv[n];
        }
#pragma unroll
        for (int kk = 0; kk < 64; kk += 32) {
            bf16x8 pa = *(const bf16x8*)(Ps + (qr0 + l4) * AST + kk + hi4 * 8);
#pragma unroll
            for (int n = 0; n < 4; ++n) {
                bf16x8 vb = *(const bf16x8*)(VTs + (n * 16 + l4) * AST + kk + hi4 * 8);
                o_acc[n] = __builtin_amdgcn_mfma_f32_16x16x32_bf16(pa, vb, o_acc[n], 0, 0, 0);
            }
        }
    }
#pragma unroll
    for (int r = 0; r < 4; ++r) {
        float inv = 1.0f / l_run[r];
        int qrow = qr0 + hi4 * 4 + r;
#pragma unroll
        for (int n = 0; n < 4; ++n)
            Ohi[(size_t)(b * L_ + qrow) * D_ + h * HD_ + n * 16 + l4] = (bfr)(o_acc[n][r] * inv);
    }
}

__global__ void rope_tables_kernel(float* __restrict__ cosT, float* __restrict__ sinT)
{
    int gid = blockIdx.x * blockDim.x + threadIdx.x;
    if (gid >= L_ * 32) return;
    int l = gid >> 5, i = gid & 31;
    float inv = powf(10000.0f, -(float)(2 * i) / (float)HD_);
    float ang = (float)l * inv;
    cosT[gid] = cosf(ang);
    sinT[gid] = sinf(ang);
}

__global__ void embed_kernel(const int* __restrict__ targets, const float* __restrict__ emb,
                             float* __restrict__ tgt, bfr* __restrict__ thi)
{
    int gid = blockIdx.x * blockDim.x + threadIdx.x;
    if (gid >= B_ * L_ * D_) return;
    int d = gid & (D_ - 1);
    int r = gid >> 9;
    int tok = targets[r];
    float x = emb[(size_t)tok * D_ + d] * 22.62741699796952f;
    tgt[gid] = x;
    thi[gid] = (bfr)x;
}

// pad mask from bf16 memory rows
__global__ void pad_kernel(const bfr* __restrict__ mem, int* __restrict__ pad)
{
    int gid = blockIdx.x * blockDim.x + threadIdx.x;
    if (gid >= B_ * T_) return;
    const bfr* p = mem + (size_t)gid * D_;
    float s = 0.f;
    for (int d0 = 0; d0 < D_; d0 += 8) {
        bf16x8 v = *(const bf16x8*)(p + d0);
#pragma unroll
        for (int j = 0; j < 8; ++j) s += fabsf((float)v[j]);
    }
    pad[gid] = (s == 0.0f) ? 1 : 0;
}

// y = LN(tgt + delta); y -> yout (f32) and thi (bf16)
__global__ __launch_bounds__(128) void ln_residual_kernel(
    const float* __restrict__ tgt, const float* __restrict__ delta,
    const float* __restrict__ g, const float* __restrict__ bb,
    float* __restrict__ yout, bfr* __restrict__ thi)
{
    const int row = blockIdx.x;
    const int t = threadIdx.x;
    __shared__ float rbuf[128];
    size_t base = (size_t)row * D_ + t * 4;
    float4 x = *(const float4*)(tgt + base);
    float4 dl = *(const float4*)(delta + base);
    x.x += dl.x; x.y += dl.y; x.z += dl.z; x.w += dl.w;
    rbuf[t] = x.x + x.y + x.z + x.w;
    __syncthreads();
    for (int off = 64; off > 0; off >>= 1) { if (t < off) rbuf[t] += rbuf[t + off]; __syncthreads(); }
    float mean = rbuf[0] * (1.0f / D_);
    __syncthreads();
    float4 d4 = {x.x - mean, x.y - mean, x.z - mean, x.w - mean};
    rbuf[t] = d4.x * d4.x + d4.y * d4.y + d4.z * d4.z + d4.w * d4.w;
    __syncthreads();
    for (int off = 64; off > 0; off >>= 1) { if (t < off) rbuf[t] += rbuf[t + off]; __syncthreads(); }
    float inv = 1.0f / sqrtf(rbuf[0] * (1.0f / D_) + 1e-5f);
    float4 g4 = *(const float4*)(g + t * 4);
    float4 b4 = *(const float4*)(bb + t * 4);
    float4 y = {d4.x * inv * g4.x + b4.x, d4.y * inv * g4.y + b4.y,
                d4.z * inv * g4.z + b4.z, d4.w * inv * g4.w + b4.w};
    *(float4*)(yout + base) = y;
    bf16x4 h4 = {(bfr)y.x, (bfr)y.y, (bfr)y.z, (bfr)y.w};
    *(bf16x4*)(thi + base) = h4;
}

__global__ void fillf_kernel(float* p, float v, size_t n)
{
    size_t gid = (size_t)blockIdx.x * 256 + threadIdx.x;
    if (gid < n) p[gid] = v;
}

extern "C" void kernel_launch(void* const* d_in, const int* in_sizes, int n_in,
                              void* d_out, int out_size, void* d_ws, size_t ws_size,
                              hipStream_t stream)
{
    const float* enc    = (const float*)d_in[0];
    const int*   tg     = (const int*)d_in[1];
    const float* emb    = (const float*)d_in[2];
    const float* inp_w  = (const float*)d_in[3];
    const float* inp_b  = (const float*)d_in[4];
    const float* out_w  = (const float*)d_in[5];
    const float* out_b  = (const float*)d_in[6];
    const float* qw     = (const float*)d_in[7];
    const float* qb     = (const float*)d_in[8];
    const float* kw     = (const float*)d_in[9];
    const float* kb     = (const float*)d_in[10];
    const float* vw     = (const float*)d_in[11];
    const float* vb     = (const float*)d_in[12];
    const float* ow     = (const float*)d_in[13];
    const float* ob     = (const float*)d_in[14];
    const float* mha_w  = (const float*)d_in[15];
    const float* mha_b  = (const float*)d_in[16];
    const float* mha_ow = (const float*)d_in[17];
    const float* mha_ob = (const float*)d_in[18];
    const float* w1     = (const float*)d_in[19];
    const float* b1     = (const float*)d_in[20];
    const float* w2     = (const float*)d_in[21];
    const float* b2     = (const float*)d_in[22];
    const float* ln1g   = (const float*)d_in[23];
    const float* ln1b   = (const float*)d_in[24];
    const float* ln2g   = (const float*)d_in[25];
    const float* ln2b   = (const float*)d_in[26];
    const float* ln3g   = (const float*)d_in[27];
    const float* ln3b   = (const float*)d_in[28];

    const int BL = B_ * L_;        // 4096
    const int BT = B_ * T_;        // 16384
    const size_t N_LOGITS = (size_t)BL * V_;
    const int D2 = D_ * D_;        // 262144

    const size_t WS_NEEDED =
        (size_t)BT * 1024 * sizeof(bfr)
        + (size_t)BL * D_ * sizeof(float)
        + (size_t)BL * D_ * sizeof(bfr)
        + (size_t)2 * L_ * 32 * sizeof(float) + (size_t)BT * sizeof(int)
        + (size_t)V_ * D_ * sizeof(bfr);
    if (ws_size < WS_NEEDED) {
        fillf_kernel<<<((size_t)out_size + 255) / 256, 256, 0, stream>>>((float*)d_out, 0.f, (size_t)out_size);
        return;
    }
    bfr*   f_KVb = (bfr*)d_ws;                          // [BT,1024]: K2 | V2
    float* f_tgt = (float*)(f_KVb + (size_t)BT * 1024);
    bfr*   tgt_hi = (bfr*)(f_tgt + (size_t)BL * D_);
    float* f_cos = (float*)(tgt_hi + (size_t)BL * D_);
    float* f_sin = f_cos + (size_t)L_ * 32;
    int*   f_pad = (int*)(f_sin + (size_t)L_ * 32);
    bfr*   ow_hi = (bfr*)(f_pad + BT);

    bfr* wp = (bfr*)d_out;
    bfr* qkvw_hi = wp;  wp += 3 * D2;
    bfr* inp_hi  = wp;  wp += D2;
    bfr* mha_hi  = wp;  wp += 3 * D2;
    bfr* o_hi    = wp;  wp += D2;
    bfr* mo_hi   = wp;  wp += D2;
    bfr* w1_hi   = wp;  wp += DFF_ * D_;
    bfr* w2_hi   = wp;  wp += D_ * DFF_;
    float* f_qkvb = (float*)wp;                 // [1536]
    float* lr    = f_qkvb + 3 * D_;
    float* f_t2  = lr;                                   // [BL,512] f32
    bfr*   qkv   = (bfr*)(f_t2 + (size_t)BL * D_);       // [BL,1536]
    bfr*   qcr   = qkv + (size_t)BL * 3 * D_;            // [BL,512]
    bfr*   t1_hi = qcr + (size_t)BL * D_;                // [BL,512]
    bfr*   ffh_hi = t1_hi + (size_t)BL * D_;             // [BL,1024]
    // prologue-only aliases in the layer region (dead before layer loop):
    bfr*   enc_hi = (bfr*)lr;                            // [BT,512] bf16
    bfr*   mem_hi = enc_hi + (size_t)BT * D_;            // [BT,512] bf16

    // single batched weight + enc convert (bf16, 8 elems/thread) + bias concat
    {
        ConvTable tab{};
        int blk = 0, ne = 0;
        auto add = [&](const float* s, bfr* d, int n) {
            tab.e[ne] = {s, d, n, blk};
            blk += n >> 11;
            ++ne;
        };
        add(qw, qkvw_hi, D2);
        add(kw, qkvw_hi + D2, D2);
        add(vw, qkvw_hi + 2 * D2, D2);
        add(inp_w, inp_hi, D2);
        add(mha_w, mha_hi, 3 * D2);
        add(ow, o_hi, D2);
        add(mha_ow, mo_hi, D2);
        add(w1, w1_hi, DFF_ * D_);
        add(w2, w2_hi, D_ * DFF_);
        add(out_w, ow_hi, V_ * D_);
        add(enc, enc_hi, BT * D_);
        tab.ne = ne;
        conv_many_kernel<<<blk, 256, 0, stream>>>(tab);
    }
    copy3_kernel<<<6, 256, 0, stream>>>(qb, kb, vb, f_qkvb);

    rope_tables_kernel<<<(L_ * 32 + 255) / 256, 256, 0, stream>>>(f_cos, f_sin);
    embed_kernel<<<(BL * D_ + 255) / 256, 256, 0, stream>>>(tg, emb, f_tgt, tgt_hi);

    // prologue (all bf16): memory, pad mask, fused K2|V2
    gemm_ps<0, 1, 128><<<(BT / 128) * (D_ / 64), 256, 0, stream>>>(enc_hi, inp_hi, inp_b, nullptr, mem_hi, BT, D_, INC_);
    pad_kernel<<<(BT + 255) / 256, 256, 0, stream>>>(mem_hi, f_pad);
    gemm_ps<0, 1, 128><<<(BT / 128) * (1024 / 64), 256, 0, stream>>>(mem_hi, mha_hi + (size_t)D2, mha_b + D_, nullptr, f_KVb, BT, 1024, D_);

    float* o_logits = (float*)d_out;
    float* o_tgt = o_logits + N_LOGITS;

    for (int layer = 0; layer < NL_; ++layer) {
        // self attention
        gemm_ps<0, 1, 64><<<(BL / 64) * (3 * D_ / 64), 256, 0, stream>>>(tgt_hi, qkvw_hi, f_qkvb, nullptr, qkv, BL, 3 * D_, D_);
        attn_wide<L_, 1><<<B_ * H_, 512, 0, stream>>>(qkv, 3 * D_, qkv + D_, qkv + 2 * D_, 3 * D_, nullptr, f_cos, f_sin, t1_hi);
        gemm_ps<0, 0, 64><<<(BL / 64) * (D_ / 64), 256, 0, stream>>>(t1_hi, o_hi, ob, f_t2, nullptr, BL, D_, D_);
        ln_residual_kernel<<<BL, 128, 0, stream>>>(f_tgt, f_t2, ln1g, ln1b, f_tgt, tgt_hi);
        // cross attention
        gemm_ps<0, 1, 64><<<(BL / 64) * (D_ / 64), 256, 0, stream>>>(tgt_hi, mha_hi, mha_b, nullptr, qcr, BL, D_, D_);
        attn_wide<T_, 0><<<B_ * H_, 512, 0, stream>>>(qcr, D_, f_KVb, f_KVb + D_, 1024, f_pad, nullptr, nullptr, t1_hi);
        gemm_ps<0, 0, 64><<<(BL / 64) * (D_ / 64), 256, 0, stream>>>(t1_hi, mo_hi, mha_ob, f_t2, nullptr, BL, D_, D_);
        ln_residual_kernel<<<BL, 128, 0, stream>>>(f_tgt, f_t2, ln2g, ln2b, f_tgt, tgt_hi);
        // FFN
        gemm_ps<1, 1, 64><<<(BL / 64) * (DFF_ / 64), 256, 0, stream>>>(tgt_hi, w1_hi, b1, nullptr, ffh_hi, BL, DFF_, D_);
        gemm_ps<0, 0, 64><<<(BL / 64) * (D_ / 64), 256, 0, stream>>>(ffh_hi, w2_hi, b2, f_t2, nullptr, BL, D_, DFF_);
        float* yout = (layer == NL_ - 1) ? o_tgt : f_tgt;
        ln_residual_kernel<<<BL, 128, 0, stream>>>(f_tgt, f_t2, ln3g, ln3b, yout, tgt_hi);
    }

    // all d_out scratch dead; logits f32
    gemm_ps<0, 0, 128><<<(BL / 128) * (V_ / 64), 256, 0, stream>>>(tgt_hi, ow_hi, out_b, o_logits, nullptr, BL, V_, D_);
}

// Round 19
// 944.965 us; speedup vs baseline: 1.5945x; 1.0240x over previous
//
#include <hip/hip_runtime.h>
#include <hip/hip_bf16.h>

#define B_ 32
#define T_ 512
#define L_ 128
#define INC_ 512
#define D_ 512
#define H_ 8
#define HD_ 64
#define NL_ 6
#define DFF_ 1024
#define V_ 8000
#define LDSK 40  // gemm LDS row stride (bf16)
#define AST 72   // attn LDS row stride (bf16)

typedef __bf16 bfr;
typedef __attribute__((ext_vector_type(8))) __bf16 bf16x8;
typedef __attribute__((ext_vector_type(4))) __bf16 bf16x4;
typedef __attribute__((ext_vector_type(4))) float f32x4;

// ---- batched f32 -> bf16 convert, 8 elems/thread (vectorized) ----
struct ConvDesc { const float* src; bfr* dst; int n; int blk0; };
struct ConvTable { ConvDesc e[12]; int ne; };

__global__ void conv_many_kernel(ConvTable tab)
{
    int b = blockIdx.x;
    for (int i = 0; i < tab.ne; ++i) {
        const ConvDesc d = tab.e[i];
        int nb = d.n >> 11;  // n / 2048 (all sizes divisible by 2048)
        if (b >= d.blk0 && b < d.blk0 + nb) {
            int g = ((b - d.blk0) * 256 + threadIdx.x) * 8;
            float4 v0 = *(const float4*)(d.src + g);
            float4 v1 = *(const float4*)(d.src + g + 4);
            bf16x8 o;
            o[0] = (bfr)v0.x; o[1] = (bfr)v0.y; o[2] = (bfr)v0.z; o[3] = (bfr)v0.w;
            o[4] = (bfr)v1.x; o[5] = (bfr)v1.y; o[6] = (bfr)v1.z; o[7] = (bfr)v1.w;
            *(bf16x8*)(d.dst + g) = o;
            return;
        }
    }
}

__global__ void copy3_kernel(const float* a, const float* b, const float* c, float* dst)
{
    int g = blockIdx.x * 256 + threadIdx.x;
    if (g < D_) dst[g] = a[g];
    else if (g < 2 * D_) dst[g] = b[g - D_];
    else if (g < 3 * D_) dst[g] = c[g - 2 * D_];
}

// bijective XCD-chunk remap (m204) + GROUP_M tile raster -> (pm, pn)
__device__ __forceinline__ void tile_map(int bid, int nbm, int nbn, int& pm, int& pn)
{
    int nwg = nbm * nbn;
    int q = nwg >> 3, r = nwg & 7;
    int xcd = bid & 7, idx = bid >> 3;
    int wgid = (xcd < r ? xcd * (q + 1) : r * (q + 1) + (xcd - r) * q) + idx;
    const int GROUP = 8;
    int per_group = GROUP * nbn;
    int gid = wgid / per_group;
    int first = gid * GROUP;
    int gsz = min(nbm - first, GROUP);
    int rem = wgid - gid * per_group;
    pm = first + rem % gsz;
    pn = rem / gsz;
}

// ---- GEMM, A bf16, W bf16 (1-term). BM in {64,128}; 1D grid + swizzle ----
// OUT: 0=f32, 1=bf16
template <int ACT, int OUT, int BM>
__global__ __launch_bounds__(256, 2) void gemm_ps(
    const bfr* __restrict__ Ahi,
    const bfr* __restrict__ Whi,
    const float* __restrict__ bias, float* __restrict__ Cf,
    bfr* __restrict__ Chi, int M, int N, int K)
{
    constexpr int MF = BM / 32;
    __shared__ bfr Ah_s[BM * LDSK];
    __shared__ bfr Wh_s[64 * LDSK];
    const int t = threadIdx.x;
    int pm, pn;
    tile_map(blockIdx.x, M / BM, N / 64, pm, pn);
    const int bm = pm * BM, bn = pn * 64;
    const int w = t >> 6, lane = t & 63;
    const int wm = w >> 1, wn = w & 1;
    const int fr = lane & 15, kq = lane >> 4;
    const int wr = t >> 2, wk = (t & 3) * 8;

    f32x4 acc[MF][2] = {};

    for (int k0 = 0; k0 < K; k0 += 32) {
        if constexpr (BM == 128) {
            const int ar = t >> 1, ah = (t & 1) * 16;
            const bfr* ap = Ahi + (size_t)(bm + ar) * K + (k0 + ah);
            *(bf16x8*)(Ah_s + ar * LDSK + ah) = *(const bf16x8*)ap;
            *(bf16x8*)(Ah_s + ar * LDSK + ah + 8) = *(const bf16x8*)(ap + 8);
        } else {
            const int ar = t >> 2, ah = (t & 3) * 8;
            *(bf16x8*)(Ah_s + ar * LDSK + ah) = *(const bf16x8*)(Ahi + (size_t)(bm + ar) * K + (k0 + ah));
        }
        *(bf16x8*)(Wh_s + wr * LDSK + wk) = *(const bf16x8*)(Whi + (size_t)(bn + wr) * K + (k0 + wk));
        __syncthreads();
        bf16x8 Afh[MF], Wfh[2];
#pragma unroll
        for (int i = 0; i < MF; ++i)
            Afh[i] = *(const bf16x8*)(Ah_s + (wm * (BM / 2) + i * 16 + fr) * LDSK + kq * 8);
#pragma unroll
        for (int j = 0; j < 2; ++j)
            Wfh[j] = *(const bf16x8*)(Wh_s + (wn * 32 + j * 16 + fr) * LDSK + kq * 8);
#pragma unroll
        for (int i = 0; i < MF; ++i)
#pragma unroll
            for (int j = 0; j < 2; ++j)
                acc[i][j] = __builtin_amdgcn_mfma_f32_16x16x32_bf16(Afh[i], Wfh[j], acc[i][j], 0, 0, 0);
        __syncthreads();
    }
#pragma unroll
    for (int i = 0; i < MF; ++i) {
        int row0 = bm + wm * (BM / 2) + i * 16 + (lane >> 4) * 4;
#pragma unroll
        for (int j = 0; j < 2; ++j) {
            int col = bn + wn * 32 + j * 16 + fr;
            float bj = bias[col];
#pragma unroll
            for (int r = 0; r < 4; ++r) {
                float v = acc[i][j][r] + bj;
                if (ACT == 1) v = 0.5f * v * (1.0f + erff(v * 0.70710678118654752f));
                size_t idx = (size_t)(row0 + r) * N + col;
                if (OUT == 0) Cf[idx] = v;
                else Chi[idx] = (bfr)v;
            }
        }
    }
}

// ---- wide-Q fused flash attention: one block per (b,h), 8 waves x 16 q rows ----
template <int TK, int CAUSAL>
__global__ __launch_bounds__(512) void attn_wide(
    const bfr* __restrict__ Qg, int qstr,
    const bfr* __restrict__ Kg, const bfr* __restrict__ Vg, int kvstr,
    const int* __restrict__ pad,
    const float* __restrict__ cosT, const float* __restrict__ sinT,
    bfr* __restrict__ Ohi)
{
    __shared__ bfr Qs[128 * AST];
    __shared__ bfr Ks[64 * AST];
    __shared__ bfr VTs[64 * AST];
    __shared__ bfr Ps[128 * AST];
    const int bh = blockIdx.x;
    const int h = bh & 7, b = bh >> 3;
    const int t = threadIdx.x;
    const int w = t >> 6, lane = t & 63;
    const int l4 = lane & 15, hi4 = lane >> 4;
    const int qr0 = w * 16;

    {
        const int srow = t >> 2, ht = t & 3;
        if (CAUSAL) {
            const bfr* qp = Qg + (size_t)(b * L_ + srow) * qstr + h * HD_ + ht * 8;
            bf16x8 a = *(const bf16x8*)qp;
            bf16x8 bb = *(const bf16x8*)(qp + 32);
            bf16x8 o1, o2;
#pragma unroll
            for (int j = 0; j < 8; ++j) {
                float c = cosT[srow * 32 + ht * 8 + j], s = sinT[srow * 32 + ht * 8 + j];
                float x1 = (float)a[j], x2 = (float)bb[j];
                o1[j] = (bfr)(x1 * c - x2 * s);
                o2[j] = (bfr)(x2 * c + x1 * s);
            }
            *(bf16x8*)(Qs + srow * AST + ht * 8) = o1;
            *(bf16x8*)(Qs + srow * AST + ht * 8 + 32) = o2;
        } else {
            const bfr* qp = Qg + (size_t)(b * L_ + srow) * qstr + h * HD_ + ht * 16;
            *(bf16x8*)(Qs + srow * AST + ht * 16) = *(const bf16x8*)qp;
            *(bf16x8*)(Qs + srow * AST + ht * 16 + 8) = *(const bf16x8*)(qp + 8);
        }
    }

    f32x4 o_acc[4] = {};
    float m_run[4], l_run[4];
#pragma unroll
    for (int r = 0; r < 4; ++r) { m_run[r] = -1e30f; l_run[r] = 0.f; }

    for (int kt = 0; kt < TK / 64; ++kt) {
        __syncthreads();
        if (t < 256) {
            const int srow = t >> 2, ht = t & 3;
            int krow = kt * 64 + srow;
            if (CAUSAL) {
                const bfr* kp = Kg + (size_t)(b * TK + krow) * kvstr + h * HD_ + ht * 8;
                bf16x8 a = *(const bf16x8*)kp;
                bf16x8 bb = *(const bf16x8*)(kp + 32);
                bf16x8 o1, o2;
#pragma unroll
                for (int j = 0; j < 8; ++j) {
                    float c = cosT[krow * 32 + ht * 8 + j], s = sinT[krow * 32 + ht * 8 + j];
                    float x1 = (float)a[j], x2 = (float)bb[j];
                    o1[j] = (bfr)(x1 * c - x2 * s);
                    o2[j] = (bfr)(x2 * c + x1 * s);
                }
                *(bf16x8*)(Ks + srow * AST + ht * 8) = o1;
                *(bf16x8*)(Ks + srow * AST + ht * 8 + 32) = o2;
            } else {
                const bfr* kp = Kg + (size_t)(b * TK + krow) * kvstr + h * HD_ + ht * 16;
                *(bf16x8*)(Ks + srow * AST + ht * 16) = *(const bf16x8*)kp;
                *(bf16x8*)(Ks + srow * AST + ht * 16 + 8) = *(const bf16x8*)(kp + 8);
            }
        } else {
            const int tt = t - 256;
            const int srow = tt >> 2, ht = tt & 3;
            const bfr* vp = Vg + (size_t)(b * TK + kt * 64 + srow) * kvstr + h * HD_ + ht * 16;
            bf16x8 v0 = *(const bf16x8*)vp;
            bf16x8 v1 = *(const bf16x8*)(vp + 8);
#pragma unroll
            for (int i = 0; i < 8; ++i) VTs[(ht * 16 + i) * AST + srow] = v0[i];
#pragma unroll
            for (int i = 0; i < 8; ++i) VTs[(ht * 16 + 8 + i) * AST + srow] = v1[i];
        }
        __syncthreads();

        f32x4 s[4] = {};
#pragma unroll
        for (int kk = 0; kk < 64; kk += 32) {
            bf16x8 a = *(const bf16x8*)(Qs + (qr0 + l4) * AST + kk + hi4 * 8);
#pragma unroll
            for (int n = 0; n < 4; ++n) {
                bf16x8 bb = *(const bf16x8*)(Ks + (n * 16 + l4) * AST + kk + hi4 * 8);
                s[n] = __builtin_amdgcn_mfma_f32_16x16x32_bf16(a, bb, s[n], 0, 0, 0);
            }
        }
        float madd[4];
        if (!CAUSAL) {
#pragma unroll
            for (int n = 0; n < 4; ++n)
                madd[n] = pad[b * TK + kt * 64 + n * 16 + l4] ? -1e30f : 0.f;
        }
#pragma unroll
        for (int r = 0; r < 4; ++r) {
            int qrow = qr0 + hi4 * 4 + r;
            float sv[4];
#pragma unroll
            for (int n = 0; n < 4; ++n) {
                float x = s[n][r] * 0.125f;
                if (CAUSAL) {
                    int col = kt * 64 + n * 16 + l4;
                    if (col > qrow) x = -1e30f;
                } else x += madd[n];
                sv[n] = x;
            }
            float mx = fmaxf(fmaxf(sv[0], sv[1]), fmaxf(sv[2], sv[3]));
#pragma unroll
            for (int off = 1; off < 16; off <<= 1) mx = fmaxf(mx, __shfl_xor(mx, off));
            float mnew = fmaxf(m_run[r], mx);
            float alpha = expf(m_run[r] - mnew);
            float pv[4], psum = 0.f;
#pragma unroll
            for (int n = 0; n < 4; ++n) { pv[n] = expf(sv[n] - mnew); psum += pv[n]; }
#pragma unroll
            for (int off = 1; off < 16; off <<= 1) psum += __shfl_xor(psum, off);
            l_run[r] = l_run[r] * alpha + psum;
            m_run[r] = mnew;
#pragma unroll
            for (int n = 0; n < 4; ++n) o_acc[n][r] *= alpha;
#pragma unroll
            for (int n = 0; n < 4; ++n)
                Ps[(qr0 + hi4 * 4 + r) * AST + n * 16 + l4] = (bfr)pv[n];
        }
#pragma unroll
        for (int kk = 0; kk < 64; kk += 32) {
            bf16x8 pa = *(const bf16x8*)(Ps + (qr0 + l4) * AST + kk + hi4 * 8);
#pragma unroll
            for (int n = 0; n < 4; ++n) {
                bf16x8 vb = *(const bf16x8*)(VTs + (n * 16 + l4) * AST + kk + hi4 * 8);
                o_acc[n] = __builtin_amdgcn_mfma_f32_16x16x32_bf16(pa, vb, o_acc[n], 0, 0, 0);
            }
        }
    }
#pragma unroll
    for (int r = 0; r < 4; ++r) {
        float inv = 1.0f / l_run[r];
        int qrow = qr0 + hi4 * 4 + r;
#pragma unroll
        for (int n = 0; n < 4; ++n)
            Ohi[(size_t)(b * L_ + qrow) * D_ + h * HD_ + n * 16 + l4] = (bfr)(o_acc[n][r] * inv);
    }
}

__global__ void rope_tables_kernel(float* __restrict__ cosT, float* __restrict__ sinT)
{
    int gid = blockIdx.x * blockDim.x + threadIdx.x;
    if (gid >= L_ * 32) return;
    int l = gid >> 5, i = gid & 31;
    float inv = powf(10000.0f, -(float)(2 * i) / (float)HD_);
    float ang = (float)l * inv;
    cosT[gid] = cosf(ang);
    sinT[gid] = sinf(ang);
}

__global__ void embed_kernel(const int* __restrict__ targets, const float* __restrict__ emb,
                             float* __restrict__ tgt, bfr* __restrict__ thi)
{
    int gid = blockIdx.x * blockDim.x + threadIdx.x;
    if (gid >= B_ * L_ * D_) return;
    int d = gid & (D_ - 1);
    int r = gid >> 9;
    int tok = targets[r];
    float x = emb[(size_t)tok * D_ + d] * 22.62741699796952f;
    tgt[gid] = x;
    thi[gid] = (bfr)x;
}

// pad mask from bf16 memory rows
__global__ void pad_kernel(const bfr* __restrict__ mem, int* __restrict__ pad)
{
    int gid = blockIdx.x * blockDim.x + threadIdx.x;
    if (gid >= B_ * T_) return;
    const bfr* p = mem + (size_t)gid * D_;
    float s = 0.f;
    for (int d0 = 0; d0 < D_; d0 += 8) {
        bf16x8 v = *(const bf16x8*)(p + d0);
#pragma unroll
        for (int j = 0; j < 8; ++j) s += fabsf((float)v[j]);
    }
    pad[gid] = (s == 0.0f) ? 1 : 0;
}

// y = LN(tgt + delta); delta bf16; y -> yout (f32) and thi (bf16)
__global__ __launch_bounds__(128) void ln_residual_kernel(
    const float* __restrict__ tgt, const bfr* __restrict__ delta,
    const float* __restrict__ g, const float* __restrict__ bb,
    float* __restrict__ yout, bfr* __restrict__ thi)
{
    const int row = blockIdx.x;
    const int t = threadIdx.x;
    __shared__ float rbuf[128];
    size_t base = (size_t)row * D_ + t * 4;
    float4 x = *(const float4*)(tgt + base);
    bf16x4 dl = *(const bf16x4*)(delta + base);
    x.x += (float)dl[0]; x.y += (float)dl[1]; x.z += (float)dl[2]; x.w += (float)dl[3];
    rbuf[t] = x.x + x.y + x.z + x.w;
    __syncthreads();
    for (int off = 64; off > 0; off >>= 1) { if (t < off) rbuf[t] += rbuf[t + off]; __syncthreads(); }
    float mean = rbuf[0] * (1.0f / D_);
    __syncthreads();
    float4 d4 = {x.x - mean, x.y - mean, x.z - mean, x.w - mean};
    rbuf[t] = d4.x * d4.x + d4.y * d4.y + d4.z * d4.z + d4.w * d4.w;
    __syncthreads();
    for (int off = 64; off > 0; off >>= 1) { if (t < off) rbuf[t] += rbuf[t + off]; __syncthreads(); }
    float inv = 1.0f / sqrtf(rbuf[0] * (1.0f / D_) + 1e-5f);
    float4 g4 = *(const float4*)(g + t * 4);
    float4 b4 = *(const float4*)(bb + t * 4);
    float4 y = {d4.x * inv * g4.x + b4.x, d4.y * inv * g4.y + b4.y,
                d4.z * inv * g4.z + b4.z, d4.w * inv * g4.w + b4.w};
    *(float4*)(yout + base) = y;
    bf16x4 h4 = {(bfr)y.x, (bfr)y.y, (bfr)y.z, (bfr)y.w};
    *(bf16x4*)(thi + base) = h4;
}

__global__ void fillf_kernel(float* p, float v, size_t n)
{
    size_t gid = (size_t)blockIdx.x * 256 + threadIdx.x;
    if (gid < n) p[gid] = v;
}

extern "C" void kernel_launch(void* const* d_in, const int* in_sizes, int n_in,
                              void* d_out, int out_size, void* d_ws, size_t ws_size,
                              hipStream_t stream)
{
    const float* enc    = (const float*)d_in[0];
    const int*   tg     = (const int*)d_in[1];
    const float* emb    = (const float*)d_in[2];
    const float* inp_w  = (const float*)d_in[3];
    const float* inp_b  = (const float*)d_in[4];
    const float* out_w  = (const float*)d_in[5];
    const float* out_b  = (const float*)d_in[6];
    const float* qw     = (const float*)d_in[7];
    const float* qb     = (const float*)d_in[8];
    const float* kw     = (const float*)d_in[9];
    const float* kb     = (const float*)d_in[10];
    const float* vw     = (const float*)d_in[11];
    const float* vb     = (const float*)d_in[12];
    const float* ow     = (const float*)d_in[13];
    const float* ob     = (const float*)d_in[14];
    const float* mha_w  = (const float*)d_in[15];
    const float* mha_b  = (const float*)d_in[16];
    const float* mha_ow = (const float*)d_in[17];
    const float* mha_ob = (const float*)d_in[18];
    const float* w1     = (const float*)d_in[19];
    const float* b1     = (const float*)d_in[20];
    const float* w2     = (const float*)d_in[21];
    const float* b2     = (const float*)d_in[22];
    const float* ln1g   = (const float*)d_in[23];
    const float* ln1b   = (const float*)d_in[24];
    const float* ln2g   = (const float*)d_in[25];
    const float* ln2b   = (const float*)d_in[26];
    const float* ln3g   = (const float*)d_in[27];
    const float* ln3b   = (const float*)d_in[28];

    const int BL = B_ * L_;        // 4096
    const int BT = B_ * T_;        // 16384
    const size_t N_LOGITS = (size_t)BL * V_;
    const int D2 = D_ * D_;        // 262144

    const size_t WS_NEEDED =
        (size_t)BT * 1024 * sizeof(bfr)
        + (size_t)BL * D_ * sizeof(float)
        + (size_t)BL * D_ * sizeof(bfr)
        + (size_t)2 * L_ * 32 * sizeof(float) + (size_t)BT * sizeof(int)
        + (size_t)V_ * D_ * sizeof(bfr);
    if (ws_size < WS_NEEDED) {
        fillf_kernel<<<((size_t)out_size + 255) / 256, 256, 0, stream>>>((float*)d_out, 0.f, (size_t)out_size);
        return;
    }
    bfr*   f_KVb = (bfr*)d_ws;                          // [BT,1024]: K2 | V2
    float* f_tgt = (float*)(f_KVb + (size_t)BT * 1024);
    bfr*   tgt_hi = (bfr*)(f_tgt + (size_t)BL * D_);
    float* f_cos = (float*)(tgt_hi + (size_t)BL * D_);
    float* f_sin = f_cos + (size_t)L_ * 32;
    int*   f_pad = (int*)(f_sin + (size_t)L_ * 32);
    bfr*   ow_hi = (bfr*)(f_pad + BT);

    bfr* wp = (bfr*)d_out;
    bfr* qkvw_hi = wp;  wp += 3 * D2;
    bfr* inp_hi  = wp;  wp += D2;
    bfr* mha_hi  = wp;  wp += 3 * D2;
    bfr* o_hi    = wp;  wp += D2;
    bfr* mo_hi   = wp;  wp += D2;
    bfr* w1_hi   = wp;  wp += DFF_ * D_;
    bfr* w2_hi   = wp;  wp += D_ * DFF_;
    float* f_qkvb = (float*)wp;                 // [1536]
    float* lr    = f_qkvb + 3 * D_;
    bfr*   t2_b  = (bfr*)lr;                             // [BL,512] bf16 delta
    bfr*   qkv   = t2_b + (size_t)BL * D_;               // [BL,1536]
    bfr*   qcr   = qkv + (size_t)BL * 3 * D_;            // [BL,512]
    bfr*   t1_hi = qcr + (size_t)BL * D_;                // [BL,512]
    bfr*   ffh_hi = t1_hi + (size_t)BL * D_;             // [BL,1024]
    // prologue-only aliases (dead before layer loop):
    bfr*   enc_hi = (bfr*)lr;                            // [BT,512] bf16
    bfr*   mem_hi = enc_hi + (size_t)BT * D_;            // [BT,512] bf16

    // single batched weight + enc convert (bf16, 8 elems/thread) + bias concat
    {
        ConvTable tab{};
        int blk = 0, ne = 0;
        auto add = [&](const float* s, bfr* d, int n) {
            tab.e[ne] = {s, d, n, blk};
            blk += n >> 11;
            ++ne;
        };
        add(qw, qkvw_hi, D2);
        add(kw, qkvw_hi + D2, D2);
        add(vw, qkvw_hi + 2 * D2, D2);
        add(inp_w, inp_hi, D2);
        add(mha_w, mha_hi, 3 * D2);
        add(ow, o_hi, D2);
        add(mha_ow, mo_hi, D2);
        add(w1, w1_hi, DFF_ * D_);
        add(w2, w2_hi, D_ * DFF_);
        add(out_w, ow_hi, V_ * D_);
        add(enc, enc_hi, BT * D_);
        tab.ne = ne;
        conv_many_kernel<<<blk, 256, 0, stream>>>(tab);
    }
    copy3_kernel<<<6, 256, 0, stream>>>(qb, kb, vb, f_qkvb);

    rope_tables_kernel<<<(L_ * 32 + 255) / 256, 256, 0, stream>>>(f_cos, f_sin);
    embed_kernel<<<(BL * D_ + 255) / 256, 256, 0, stream>>>(tg, emb, f_tgt, tgt_hi);

    // prologue (all bf16): memory, pad mask, fused K2|V2
    gemm_ps<0, 1, 128><<<(BT / 128) * (D_ / 64), 256, 0, stream>>>(enc_hi, inp_hi, inp_b, nullptr, mem_hi, BT, D_, INC_);
    pad_kernel<<<(BT + 255) / 256, 256, 0, stream>>>(mem_hi, f_pad);
    gemm_ps<0, 1, 128><<<(BT / 128) * (1024 / 64), 256, 0, stream>>>(mem_hi, mha_hi + (size_t)D2, mha_b + D_, nullptr, f_KVb, BT, 1024, D_);

    float* o_logits = (float*)d_out;
    float* o_tgt = o_logits + N_LOGITS;

    for (int layer = 0; layer < NL_; ++layer) {
        // self attention
        gemm_ps<0, 1, 64><<<(BL / 64) * (3 * D_ / 64), 256, 0, stream>>>(tgt_hi, qkvw_hi, f_qkvb, nullptr, qkv, BL, 3 * D_, D_);
        attn_wide<L_, 1><<<B_ * H_, 512, 0, stream>>>(qkv, 3 * D_, qkv + D_, qkv + 2 * D_, 3 * D_, nullptr, f_cos, f_sin, t1_hi);
        gemm_ps<0, 1, 64><<<(BL / 64) * (D_ / 64), 256, 0, stream>>>(t1_hi, o_hi, ob, nullptr, t2_b, BL, D_, D_);
        ln_residual_kernel<<<BL, 128, 0, stream>>>(f_tgt, t2_b, ln1g, ln1b, f_tgt, tgt_hi);
        // cross attention
        gemm_ps<0, 1, 64><<<(BL / 64) * (D_ / 64), 256, 0, stream>>>(tgt_hi, mha_hi, mha_b, nullptr, qcr, BL, D_, D_);
        attn_wide<T_, 0><<<B_ * H_, 512, 0, stream>>>(qcr, D_, f_KVb, f_KVb + D_, 1024, f_pad, nullptr, nullptr, t1_hi);
        gemm_ps<0, 1, 64><<<(BL / 64) * (D_ / 64), 256, 0, stream>>>(t1_hi, mo_hi, mha_ob, nullptr, t2_b, BL, D_, D_);
        ln_residual_kernel<<<BL, 128, 0, stream>>>(f_tgt, t2_b, ln2g, ln2b, f_tgt, tgt_hi);
        // FFN
        gemm_ps<1, 1, 64><<<(BL / 64) * (DFF_ / 64), 256, 0, stream>>>(tgt_hi, w1_hi, b1, nullptr, ffh_hi, BL, DFF_, D_);
        gemm_ps<0, 1, 64><<<(BL / 64) * (D_ / 64), 256, 0, stream>>>(ffh_hi, w2_hi, b2, nullptr, t2_b, BL, D_, DFF_);
        float* yout = (layer == NL_ - 1) ? o_tgt : f_tgt;
        ln_residual_kernel<<<BL, 128, 0, stream>>>(f_tgt, t2_b, ln3g, ln3b, yout, tgt_hi);
    }

    // all d_out scratch dead; logits f32
    gemm_ps<0, 0, 128><<<(BL / 128) * (V_ / 64), 256, 0, stream>>>(tgt_hi, ow_hi, out_b, o_logits, nullptr, BL, V_, D_);
}

// Round 20
// 914.687 us; speedup vs baseline: 1.6473x; 1.0331x over previous
//
#include <hip/hip_runtime.h>
#include <hip/hip_bf16.h>

#define B_ 32
#define T_ 512
#define L_ 128
#define INC_ 512
#define D_ 512
#define H_ 8
#define HD_ 64
#define NL_ 6
#define DFF_ 1024
#define V_ 8000
#define LDSK 40  // gemm LDS row stride (bf16)
#define AST 72   // attn LDS row stride (bf16)

typedef __bf16 bfr;
typedef __attribute__((ext_vector_type(8))) __bf16 bf16x8;
typedef __attribute__((ext_vector_type(4))) __bf16 bf16x4;
typedef __attribute__((ext_vector_type(4))) float f32x4;

// ---- batched f32 -> bf16 convert, 8 elems/thread (vectorized) ----
struct ConvDesc { const float* src; bfr* dst; int n; int blk0; };
struct ConvTable { ConvDesc e[12]; int ne; };

__global__ void conv_many_kernel(ConvTable tab)
{
    int b = blockIdx.x;
    for (int i = 0; i < tab.ne; ++i) {
        const ConvDesc d = tab.e[i];
        int nb = d.n >> 11;
        if (b >= d.blk0 && b < d.blk0 + nb) {
            int g = ((b - d.blk0) * 256 + threadIdx.x) * 8;
            float4 v0 = *(const float4*)(d.src + g);
            float4 v1 = *(const float4*)(d.src + g + 4);
            bf16x8 o;
            o[0] = (bfr)v0.x; o[1] = (bfr)v0.y; o[2] = (bfr)v0.z; o[3] = (bfr)v0.w;
            o[4] = (bfr)v1.x; o[5] = (bfr)v1.y; o[6] = (bfr)v1.z; o[7] = (bfr)v1.w;
            *(bf16x8*)(d.dst + g) = o;
            return;
        }
    }
}

__global__ void copy3_kernel(const float* a, const float* b, const float* c, float* dst)
{
    int g = blockIdx.x * 256 + threadIdx.x;
    if (g < D_) dst[g] = a[g];
    else if (g < 2 * D_) dst[g] = b[g - D_];
    else if (g < 3 * D_) dst[g] = c[g - 2 * D_];
}

// bijective XCD-chunk remap (m204) + GROUP_M tile raster -> (pm, pn)
__device__ __forceinline__ void tile_map(int bid, int nbm, int nbn, int& pm, int& pn)
{
    int nwg = nbm * nbn;
    int q = nwg >> 3, r = nwg & 7;
    int xcd = bid & 7, idx = bid >> 3;
    int wgid = (xcd < r ? xcd * (q + 1) : r * (q + 1) + (xcd - r) * q) + idx;
    const int GROUP = 8;
    int per_group = GROUP * nbn;
    int gid = wgid / per_group;
    int first = gid * GROUP;
    int gsz = min(nbm - first, GROUP);
    int rem = wgid - gid * per_group;
    pm = first + rem % gsz;
    pn = rem / gsz;
}

// ---- GEMM, A bf16, W bf16 (1-term). BM in {64,128}; 1D grid + swizzle ----
// OUT: 0=f32, 1=bf16
template <int ACT, int OUT, int BM>
__global__ __launch_bounds__(256, 2) void gemm_ps(
    const bfr* __restrict__ Ahi,
    const bfr* __restrict__ Whi,
    const float* __restrict__ bias, float* __restrict__ Cf,
    bfr* __restrict__ Chi, int M, int N, int K)
{
    constexpr int MF = BM / 32;
    __shared__ bfr Ah_s[BM * LDSK];
    __shared__ bfr Wh_s[64 * LDSK];
    const int t = threadIdx.x;
    int pm, pn;
    tile_map(blockIdx.x, M / BM, N / 64, pm, pn);
    const int bm = pm * BM, bn = pn * 64;
    const int w = t >> 6, lane = t & 63;
    const int wm = w >> 1, wn = w & 1;
    const int fr = lane & 15, kq = lane >> 4;
    const int wr = t >> 2, wk = (t & 3) * 8;

    f32x4 acc[MF][2] = {};

    for (int k0 = 0; k0 < K; k0 += 32) {
        if constexpr (BM == 128) {
            const int ar = t >> 1, ah = (t & 1) * 16;
            const bfr* ap = Ahi + (size_t)(bm + ar) * K + (k0 + ah);
            *(bf16x8*)(Ah_s + ar * LDSK + ah) = *(const bf16x8*)ap;
            *(bf16x8*)(Ah_s + ar * LDSK + ah + 8) = *(const bf16x8*)(ap + 8);
        } else {
            const int ar = t >> 2, ah = (t & 3) * 8;
            *(bf16x8*)(Ah_s + ar * LDSK + ah) = *(const bf16x8*)(Ahi + (size_t)(bm + ar) * K + (k0 + ah));
        }
        *(bf16x8*)(Wh_s + wr * LDSK + wk) = *(const bf16x8*)(Whi + (size_t)(bn + wr) * K + (k0 + wk));
        __syncthreads();
        bf16x8 Afh[MF], Wfh[2];
#pragma unroll
        for (int i = 0; i < MF; ++i)
            Afh[i] = *(const bf16x8*)(Ah_s + (wm * (BM / 2) + i * 16 + fr) * LDSK + kq * 8);
#pragma unroll
        for (int j = 0; j < 2; ++j)
            Wfh[j] = *(const bf16x8*)(Wh_s + (wn * 32 + j * 16 + fr) * LDSK + kq * 8);
#pragma unroll
        for (int i = 0; i < MF; ++i)
#pragma unroll
            for (int j = 0; j < 2; ++j)
                acc[i][j] = __builtin_amdgcn_mfma_f32_16x16x32_bf16(Afh[i], Wfh[j], acc[i][j], 0, 0, 0);
        __syncthreads();
    }
#pragma unroll
    for (int i = 0; i < MF; ++i) {
        int row0 = bm + wm * (BM / 2) + i * 16 + (lane >> 4) * 4;
#pragma unroll
        for (int j = 0; j < 2; ++j) {
            int col = bn + wn * 32 + j * 16 + fr;
            float bj = bias[col];
#pragma unroll
            for (int r = 0; r < 4; ++r) {
                float v = acc[i][j][r] + bj;
                if (ACT == 1) v = 0.5f * v * (1.0f + erff(v * 0.70710678118654752f));
                size_t idx = (size_t)(row0 + r) * N + col;
                if (OUT == 0) Cf[idx] = v;
                else Chi[idx] = (bfr)v;
            }
        }
    }
}

// ---- wide-Q flash attention, double-buffered reg-staged K/V, 1 barrier/tile ----
// One block per (b,h); 8 waves x 16 q rows. K staged by t<256, V^T by t>=256.
template <int TK, int CAUSAL>
__global__ __launch_bounds__(512) void attn_wide(
    const bfr* __restrict__ Qg, int qstr,
    const bfr* __restrict__ Kg, const bfr* __restrict__ Vg, int kvstr,
    const int* __restrict__ pad,
    const float* __restrict__ cosT, const float* __restrict__ sinT,
    bfr* __restrict__ Ohi)
{
    __shared__ bfr Qs[128 * AST];
    __shared__ bfr Ks[2][64 * AST];
    __shared__ bfr VTs[2][64 * AST];
    __shared__ bfr Ps[128 * AST];
    const int bh = blockIdx.x;
    const int h = bh & 7, b = bh >> 3;
    const int t = threadIdx.x;
    const int w = t >> 6, lane = t & 63;
    const int l4 = lane & 15, hi4 = lane >> 4;
    const int qr0 = w * 16;
    const bool kstage = t < 256;
    const int srow = (t & 255) >> 2, ht = t & 3;  // staging row / quarter

    // stage Q (all 512 threads, 4 threads/row over 128 rows)
    {
        const int qrow = t >> 2, qh = t & 3;
        if (CAUSAL) {
            const bfr* qp = Qg + (size_t)(b * L_ + qrow) * qstr + h * HD_ + qh * 8;
            bf16x8 a = *(const bf16x8*)qp;
            bf16x8 bb = *(const bf16x8*)(qp + 32);
            bf16x8 o1, o2;
#pragma unroll
            for (int j = 0; j < 8; ++j) {
                float c = cosT[qrow * 32 + qh * 8 + j], s = sinT[qrow * 32 + qh * 8 + j];
                float x1 = (float)a[j], x2 = (float)bb[j];
                o1[j] = (bfr)(x1 * c - x2 * s);
                o2[j] = (bfr)(x2 * c + x1 * s);
            }
            *(bf16x8*)(Qs + qrow * AST + qh * 8) = o1;
            *(bf16x8*)(Qs + qrow * AST + qh * 8 + 32) = o2;
        } else {
            const bfr* qp = Qg + (size_t)(b * L_ + qrow) * qstr + h * HD_ + qh * 16;
            *(bf16x8*)(Qs + qrow * AST + qh * 16) = *(const bf16x8*)qp;
            *(bf16x8*)(Qs + qrow * AST + qh * 16 + 8) = *(const bf16x8*)(qp + 8);
        }
    }

    const int NT = TK / 64;
    bf16x8 r0, r1;

    // ---- load + write tile 0 into buffer 0 ----
    {
        int nrow = srow;
        if (kstage) {
            if (CAUSAL) {
                const bfr* kp = Kg + (size_t)(b * TK + nrow) * kvstr + h * HD_ + ht * 8;
                bf16x8 a = *(const bf16x8*)kp;
                bf16x8 bb = *(const bf16x8*)(kp + 32);
#pragma unroll
                for (int j = 0; j < 8; ++j) {
                    float c = cosT[nrow * 32 + ht * 8 + j], s = sinT[nrow * 32 + ht * 8 + j];
                    float x1 = (float)a[j], x2 = (float)bb[j];
                    r0[j] = (bfr)(x1 * c - x2 * s);
                    r1[j] = (bfr)(x2 * c + x1 * s);
                }
                *(bf16x8*)(Ks[0] + srow * AST + ht * 8) = r0;
                *(bf16x8*)(Ks[0] + srow * AST + ht * 8 + 32) = r1;
            } else {
                const bfr* kp = Kg + (size_t)(b * TK + nrow) * kvstr + h * HD_ + ht * 16;
                *(bf16x8*)(Ks[0] + srow * AST + ht * 16) = *(const bf16x8*)kp;
                *(bf16x8*)(Ks[0] + srow * AST + ht * 16 + 8) = *(const bf16x8*)(kp + 8);
            }
        } else {
            const bfr* vp = Vg + (size_t)(b * TK + nrow) * kvstr + h * HD_ + ht * 16;
            bf16x8 v0 = *(const bf16x8*)vp;
            bf16x8 v1 = *(const bf16x8*)(vp + 8);
#pragma unroll
            for (int i = 0; i < 8; ++i) VTs[0][(ht * 16 + i) * AST + srow] = v0[i];
#pragma unroll
            for (int i = 0; i < 8; ++i) VTs[0][(ht * 16 + 8 + i) * AST + srow] = v1[i];
        }
    }
    __syncthreads();  // Q + tile0 staged

    f32x4 o_acc[4] = {};
    float m_run[4], l_run[4];
#pragma unroll
    for (int r = 0; r < 4; ++r) { m_run[r] = -1e30f; l_run[r] = 0.f; }

    for (int kt = 0; kt < NT; ++kt) {
        const int cur = kt & 1;
        const bool have_next = (kt + 1 < NT);
        // issue next-tile loads into regs (HBM latency hides under compute)
        if (have_next) {
            int nrow = (kt + 1) * 64 + srow;
            if (kstage) {
                if (CAUSAL) {
                    const bfr* kp = Kg + (size_t)(b * TK + nrow) * kvstr + h * HD_ + ht * 8;
                    bf16x8 a = *(const bf16x8*)kp;
                    bf16x8 bb = *(const bf16x8*)(kp + 32);
#pragma unroll
                    for (int j = 0; j < 8; ++j) {
                        float c = cosT[nrow * 32 + ht * 8 + j], s = sinT[nrow * 32 + ht * 8 + j];
                        float x1 = (float)a[j], x2 = (float)bb[j];
                        r0[j] = (bfr)(x1 * c - x2 * s);
                        r1[j] = (bfr)(x2 * c + x1 * s);
                    }
                } else {
                    const bfr* kp = Kg + (size_t)(b * TK + nrow) * kvstr + h * HD_ + ht * 16;
                    r0 = *(const bf16x8*)kp;
                    r1 = *(const bf16x8*)(kp + 8);
                }
            } else {
                const bfr* vp = Vg + (size_t)(b * TK + nrow) * kvstr + h * HD_ + ht * 16;
                r0 = *(const bf16x8*)vp;
                r1 = *(const bf16x8*)(vp + 8);
            }
        }
        // compute (skip waves whose q-rows are fully masked for this tile)
        const bool active = !CAUSAL || (kt * 64 <= qr0 + 15);
        if (active) {
            f32x4 s[4] = {};
#pragma unroll
            for (int kk = 0; kk < 64; kk += 32) {
                bf16x8 a = *(const bf16x8*)(Qs + (qr0 + l4) * AST + kk + hi4 * 8);
#pragma unroll
                for (int n = 0; n < 4; ++n) {
                    bf16x8 bb = *(const bf16x8*)(Ks[cur] + (n * 16 + l4) * AST + kk + hi4 * 8);
                    s[n] = __builtin_amdgcn_mfma_f32_16x16x32_bf16(a, bb, s[n], 0, 0, 0);
                }
            }
            float madd[4];
            if (!CAUSAL) {
#pragma unroll
                for (int n = 0; n < 4; ++n)
                    madd[n] = pad[b * TK + kt * 64 + n * 16 + l4] ? -1e30f : 0.f;
            }
#pragma unroll
            for (int r = 0; r < 4; ++r) {
                int qrow = qr0 + hi4 * 4 + r;
                float sv[4];
#pragma unroll
                for (int n = 0; n < 4; ++n) {
                    float x = s[n][r] * 0.125f;
                    if (CAUSAL) {
                        int col = kt * 64 + n * 16 + l4;
                        if (col > qrow) x = -1e30f;
                    } else x += madd[n];
                    sv[n] = x;
                }
                float mx = fmaxf(fmaxf(sv[0], sv[1]), fmaxf(sv[2], sv[3]));
#pragma unroll
                for (int off = 1; off < 16; off <<= 1) mx = fmaxf(mx, __shfl_xor(mx, off));
                float mnew = fmaxf(m_run[r], mx);
                float alpha = expf(m_run[r] - mnew);
                float pv[4], psum = 0.f;
#pragma unroll
                for (int n = 0; n < 4; ++n) { pv[n] = expf(sv[n] - mnew); psum += pv[n]; }
#pragma unroll
                for (int off = 1; off < 16; off <<= 1) psum += __shfl_xor(psum, off);
                l_run[r] = l_run[r] * alpha + psum;
                m_run[r] = mnew;
#pragma unroll
                for (int n = 0; n < 4; ++n) o_acc[n][r] *= alpha;
#pragma unroll
                for (int n = 0; n < 4; ++n)
                    Ps[(qr0 + hi4 * 4 + r) * AST + n * 16 + l4] = (bfr)pv[n];
            }
#pragma unroll
            for (int kk = 0; kk < 64; kk += 32) {
                bf16x8 pa = *(const bf16x8*)(Ps + (qr0 + l4) * AST + kk + hi4 * 8);
#pragma unroll
                for (int n = 0; n < 4; ++n) {
                    bf16x8 vb = *(const bf16x8*)(VTs[cur] + (n * 16 + l4) * AST + kk + hi4 * 8);
                    o_acc[n] = __builtin_amdgcn_mfma_f32_16x16x32_bf16(pa, vb, o_acc[n], 0, 0, 0);
                }
            }
        }
        // write next tile into the other buffer (safe: last read pre-previous barrier)
        if (have_next) {
            const int nxt = cur ^ 1;
            if (kstage) {
                if (CAUSAL) {
                    *(bf16x8*)(Ks[nxt] + srow * AST + ht * 8) = r0;
                    *(bf16x8*)(Ks[nxt] + srow * AST + ht * 8 + 32) = r1;
                } else {
                    *(bf16x8*)(Ks[nxt] + srow * AST + ht * 16) = r0;
                    *(bf16x8*)(Ks[nxt] + srow * AST + ht * 16 + 8) = r1;
                }
            } else {
#pragma unroll
                for (int i = 0; i < 8; ++i) VTs[nxt][(ht * 16 + i) * AST + srow] = r0[i];
#pragma unroll
                for (int i = 0; i < 8; ++i) VTs[nxt][(ht * 16 + 8 + i) * AST + srow] = r1[i];
            }
        }
        __syncthreads();
    }
#pragma unroll
    for (int r = 0; r < 4; ++r) {
        float inv = 1.0f / l_run[r];
        int qrow = qr0 + hi4 * 4 + r;
#pragma unroll
        for (int n = 0; n < 4; ++n)
            Ohi[(size_t)(b * L_ + qrow) * D_ + h * HD_ + n * 16 + l4] = (bfr)(o_acc[n][r] * inv);
    }
}

__global__ void rope_tables_kernel(float* __restrict__ cosT, float* __restrict__ sinT)
{
    int gid = blockIdx.x * blockDim.x + threadIdx.x;
    if (gid >= L_ * 32) return;
    int l = gid >> 5, i = gid & 31;
    float inv = powf(10000.0f, -(float)(2 * i) / (float)HD_);
    float ang = (float)l * inv;
    cosT[gid] = cosf(ang);
    sinT[gid] = sinf(ang);
}

__global__ void embed_kernel(const int* __restrict__ targets, const float* __restrict__ emb,
                             float* __restrict__ tgt, bfr* __restrict__ thi)
{
    int gid = blockIdx.x * blockDim.x + threadIdx.x;
    if (gid >= B_ * L_ * D_) return;
    int d = gid & (D_ - 1);
    int r = gid >> 9;
    int tok = targets[r];
    float x = emb[(size_t)tok * D_ + d] * 22.62741699796952f;
    tgt[gid] = x;
    thi[gid] = (bfr)x;
}

// pad mask from bf16 memory rows
__global__ void pad_kernel(const bfr* __restrict__ mem, int* __restrict__ pad)
{
    int gid = blockIdx.x * blockDim.x + threadIdx.x;
    if (gid >= B_ * T_) return;
    const bfr* p = mem + (size_t)gid * D_;
    float s = 0.f;
    for (int d0 = 0; d0 < D_; d0 += 8) {
        bf16x8 v = *(const bf16x8*)(p + d0);
#pragma unroll
        for (int j = 0; j < 8; ++j) s += fabsf((float)v[j]);
    }
    pad[gid] = (s == 0.0f) ? 1 : 0;
}

// y = LN(tgt + delta); delta bf16; y -> yout (f32) and thi (bf16)
__global__ __launch_bounds__(128) void ln_residual_kernel(
    const float* __restrict__ tgt, const bfr* __restrict__ delta,
    const float* __restrict__ g, const float* __restrict__ bb,
    float* __restrict__ yout, bfr* __restrict__ thi)
{
    const int row = blockIdx.x;
    const int t = threadIdx.x;
    __shared__ float rbuf[128];
    size_t base = (size_t)row * D_ + t * 4;
    float4 x = *(const float4*)(tgt + base);
    bf16x4 dl = *(const bf16x4*)(delta + base);
    x.x += (float)dl[0]; x.y += (float)dl[1]; x.z += (float)dl[2]; x.w += (float)dl[3];
    rbuf[t] = x.x + x.y + x.z + x.w;
    __syncthreads();
    for (int off = 64; off > 0; off >>= 1) { if (t < off) rbuf[t] += rbuf[t + off]; __syncthreads(); }
    float mean = rbuf[0] * (1.0f / D_);
    __syncthreads();
    float4 d4 = {x.x - mean, x.y - mean, x.z - mean, x.w - mean};
    rbuf[t] = d4.x * d4.x + d4.y * d4.y + d4.z * d4.z + d4.w * d4.w;
    __syncthreads();
    for (int off = 64; off > 0; off >>= 1) { if (t < off) rbuf[t] += rbuf[t + off]; __syncthreads(); }
    float inv = 1.0f / sqrtf(rbuf[0] * (1.0f / D_) + 1e-5f);
    float4 g4 = *(const float4*)(g + t * 4);
    float4 b4 = *(const float4*)(bb + t * 4);
    float4 y = {d4.x * inv * g4.x + b4.x, d4.y * inv * g4.y + b4.y,
                d4.z * inv * g4.z + b4.z, d4.w * inv * g4.w + b4.w};
    *(float4*)(yout + base) = y;
    bf16x4 h4 = {(bfr)y.x, (bfr)y.y, (bfr)y.z, (bfr)y.w};
    *(bf16x4*)(thi + base) = h4;
}

__global__ void fillf_kernel(float* p, float v, size_t n)
{
    size_t gid = (size_t)blockIdx.x * 256 + threadIdx.x;
    if (gid < n) p[gid] = v;
}

extern "C" void kernel_launch(void* const* d_in, const int* in_sizes, int n_in,
                              void* d_out, int out_size, void* d_ws, size_t ws_size,
                              hipStream_t stream)
{
    const float* enc    = (const float*)d_in[0];
    const int*   tg     = (const int*)d_in[1];
    const float* emb    = (const float*)d_in[2];
    const float* inp_w  = (const float*)d_in[3];
    const float* inp_b  = (const float*)d_in[4];
    const float* out_w  = (const float*)d_in[5];
    const float* out_b  = (const float*)d_in[6];
    const float* qw     = (const float*)d_in[7];
    const float* qb     = (const float*)d_in[8];
    const float* kw     = (const float*)d_in[9];
    const float* kb     = (const float*)d_in[10];
    const float* vw     = (const float*)d_in[11];
    const float* vb     = (const float*)d_in[12];
    const float* ow     = (const float*)d_in[13];
    const float* ob     = (const float*)d_in[14];
    const float* mha_w  = (const float*)d_in[15];
    const float* mha_b  = (const float*)d_in[16];
    const float* mha_ow = (const float*)d_in[17];
    const float* mha_ob = (const float*)d_in[18];
    const float* w1     = (const float*)d_in[19];
    const float* b1     = (const float*)d_in[20];
    const float* w2     = (const float*)d_in[21];
    const float* b2     = (const float*)d_in[22];
    const float* ln1g   = (const float*)d_in[23];
    const float* ln1b   = (const float*)d_in[24];
    const float* ln2g   = (const float*)d_in[25];
    const float* ln2b   = (const float*)d_in[26];
    const float* ln3g   = (const float*)d_in[27];
    const float* ln3b   = (const float*)d_in[28];

    const int BL = B_ * L_;        // 4096
    const int BT = B_ * T_;        // 16384
    const size_t N_LOGITS = (size_t)BL * V_;
    const int D2 = D_ * D_;        // 262144

    const size_t WS_NEEDED =
        (size_t)BT * 1024 * sizeof(bfr)
        + (size_t)BL * D_ * sizeof(float)
        + (size_t)BL * D_ * sizeof(bfr)
        + (size_t)2 * L_ * 32 * sizeof(float) + (size_t)BT * sizeof(int)
        + (size_t)V_ * D_ * sizeof(bfr);
    if (ws_size < WS_NEEDED) {
        fillf_kernel<<<((size_t)out_size + 255) / 256, 256, 0, stream>>>((float*)d_out, 0.f, (size_t)out_size);
        return;
    }
    bfr*   f_KVb = (bfr*)d_ws;                          // [BT,1024]: K2 | V2
    float* f_tgt = (float*)(f_KVb + (size_t)BT * 1024);
    bfr*   tgt_hi = (bfr*)(f_tgt + (size_t)BL * D_);
    float* f_cos = (float*)(tgt_hi + (size_t)BL * D_);
    float* f_sin = f_cos + (size_t)L_ * 32;
    int*   f_pad = (int*)(f_sin + (size_t)L_ * 32);
    bfr*   ow_hi = (bfr*)(f_pad + BT);

    bfr* wp = (bfr*)d_out;
    bfr* qkvw_hi = wp;  wp += 3 * D2;
    bfr* inp_hi  = wp;  wp += D2;
    bfr* mha_hi  = wp;  wp += 3 * D2;
    bfr* o_hi    = wp;  wp += D2;
    bfr* mo_hi   = wp;  wp += D2;
    bfr* w1_hi   = wp;  wp += DFF_ * D_;
    bfr* w2_hi   = wp;  wp += D_ * DFF_;
    float* f_qkvb = (float*)wp;                 // [1536]
    float* lr    = f_qkvb + 3 * D_;
    bfr*   t2_b  = (bfr*)lr;                             // [BL,512] bf16 delta
    bfr*   qkv   = t2_b + (size_t)BL * D_;               // [BL,1536]
    bfr*   qcr   = qkv + (size_t)BL * 3 * D_;            // [BL,512]
    bfr*   t1_hi = qcr + (size_t)BL * D_;                // [BL,512]
    bfr*   ffh_hi = t1_hi + (size_t)BL * D_;             // [BL,1024]
    // prologue-only aliases (dead before layer loop):
    bfr*   enc_hi = (bfr*)lr;                            // [BT,512] bf16
    bfr*   mem_hi = enc_hi + (size_t)BT * D_;            // [BT,512] bf16

    // single batched weight + enc convert + bias concat
    {
        ConvTable tab{};
        int blk = 0, ne = 0;
        auto add = [&](const float* s, bfr* d, int n) {
            tab.e[ne] = {s, d, n, blk};
            blk += n >> 11;
            ++ne;
        };
        add(qw, qkvw_hi, D2);
        add(kw, qkvw_hi + D2, D2);
        add(vw, qkvw_hi + 2 * D2, D2);
        add(inp_w, inp_hi, D2);
        add(mha_w, mha_hi, 3 * D2);
        add(ow, o_hi, D2);
        add(mha_ow, mo_hi, D2);
        add(w1, w1_hi, DFF_ * D_);
        add(w2, w2_hi, D_ * DFF_);
        add(out_w, ow_hi, V_ * D_);
        add(enc, enc_hi, BT * D_);
        tab.ne = ne;
        conv_many_kernel<<<blk, 256, 0, stream>>>(tab);
    }
    copy3_kernel<<<6, 256, 0, stream>>>(qb, kb, vb, f_qkvb);

    rope_tables_kernel<<<(L_ * 32 + 255) / 256, 256, 0, stream>>>(f_cos, f_sin);
    embed_kernel<<<(BL * D_ + 255) / 256, 256, 0, stream>>>(tg, emb, f_tgt, tgt_hi);

    // prologue (all bf16): memory, pad mask, fused K2|V2
    gemm_ps<0, 1, 128><<<(BT / 128) * (D_ / 64), 256, 0, stream>>>(enc_hi, inp_hi, inp_b, nullptr, mem_hi, BT, D_, INC_);
    pad_kernel<<<(BT + 255) / 256, 256, 0, stream>>>(mem_hi, f_pad);
    gemm_ps<0, 1, 128><<<(BT / 128) * (1024 / 64), 256, 0, stream>>>(mem_hi, mha_hi + (size_t)D2, mha_b + D_, nullptr, f_KVb, BT, 1024, D_);

    float* o_logits = (float*)d_out;
    float* o_tgt = o_logits + N_LOGITS;

    for (int layer = 0; layer < NL_; ++layer) {
        // self attention
        gemm_ps<0, 1, 64><<<(BL / 64) * (3 * D_ / 64), 256, 0, stream>>>(tgt_hi, qkvw_hi, f_qkvb, nullptr, qkv, BL, 3 * D_, D_);
        attn_wide<L_, 1><<<B_ * H_, 512, 0, stream>>>(qkv, 3 * D_, qkv + D_, qkv + 2 * D_, 3 * D_, nullptr, f_cos, f_sin, t1_hi);
        gemm_ps<0, 1, 64><<<(BL / 64) * (D_ / 64), 256, 0, stream>>>(t1_hi, o_hi, ob, nullptr, t2_b, BL, D_, D_);
        ln_residual_kernel<<<BL, 128, 0, stream>>>(f_tgt, t2_b, ln1g, ln1b, f_tgt, tgt_hi);
        // cross attention
        gemm_ps<0, 1, 64><<<(BL / 64) * (D_ / 64), 256, 0, stream>>>(tgt_hi, mha_hi, mha_b, nullptr, qcr, BL, D_, D_);
        attn_wide<T_, 0><<<B_ * H_, 512, 0, stream>>>(qcr, D_, f_KVb, f_KVb + D_, 1024, f_pad, nullptr, nullptr, t1_hi);
        gemm_ps<0, 1, 64><<<(BL / 64) * (D_ / 64), 256, 0, stream>>>(t1_hi, mo_hi, mha_ob, nullptr, t2_b, BL, D_, D_);
        ln_residual_kernel<<<BL, 128, 0, stream>>>(f_tgt, t2_b, ln2g, ln2b, f_tgt, tgt_hi);
        // FFN
        gemm_ps<1, 1, 64><<<(BL / 64) * (DFF_ / 64), 256, 0, stream>>>(tgt_hi, w1_hi, b1, nullptr, ffh_hi, BL, DFF_, D_);
        gemm_ps<0, 1, 64><<<(BL / 64) * (D_ / 64), 256, 0, stream>>>(ffh_hi, w2_hi, b2, nullptr, t2_b, BL, D_, DFF_);
        float* yout = (layer == NL_ - 1) ? o_tgt : f_tgt;
        ln_residual_kernel<<<BL, 128, 0, stream>>>(f_tgt, t2_b, ln3g, ln3b, yout, tgt_hi);
    }

    // all d_out scratch dead; logits f32
    gemm_ps<0, 0, 128><<<(BL / 128) * (V_ / 64), 256, 0, stream>>>(tgt_hi, ow_hi, out_b, o_logits, nullptr, BL, V_, D_);
}